// Round 1
// baseline (1374.858 us; speedup 1.0000x reference)
//
#include <hip/hip_runtime.h>
#include <hip/hip_bf16.h>
#include <cstdint>

#define NB 64        // batch
#define ND 64        // DIM
#define NH 8         // heads
#define DH 64        // dim_head
#define NIN 512      // inner
#define NMLP 256
#define NDEPTH 4
#define NPATCH 225
#define NTOK 226
#define NSB 128      // 2*B (both streams batched)
#define NROWS (NSB*NTOK)   // 28928

#define VP 232       // attention Vt LDS pitch (bf16 units); 232=8*29 keeps rows 16B-aligned,
                     // dword row-stride 116 ≡ 20 (mod 32) -> ~2-way banks (vs 24 @ VP=240)

typedef __attribute__((ext_vector_type(8))) short bfrag8;
typedef __attribute__((ext_vector_type(4))) float ffrag4;

// RNE bf16: bit-exact vs __float2bfloat16 for finite inputs, 3 VALU ops.
__device__ __forceinline__ unsigned short f2b(float f) {
  uint32_t u; __builtin_memcpy(&u, &f, 4);
  u += 0x7fff + ((u >> 16) & 1);
  return (unsigned short)(u >> 16);
}

// pack 2 f32 -> 2 bf16 in one u32 (lo = first arg), RNE — single VALU op
__device__ __forceinline__ unsigned pk2(float lo, float hi) {
  unsigned r;
  asm("v_cvt_pk_bf16_f32 %0, %1, %2" : "=v"(r) : "v"(lo), "v"(hi));
  return r;
}

// ---- fusion-matrix diagonal: sdfm[b][d] = sqrt(sigmoid(x @ fmg_w[:,65d])) ----
__global__ void k_dfm(const float* __restrict__ hsi, const float* __restrict__ lidar,
                      const float* __restrict__ fmg_w, float* __restrict__ sdfm) {
  __shared__ float xc[128];
  int b = blockIdx.x, t = threadIdx.x;
  const float* src = (t < 64) ? hsi : lidar;
  int d = t & 63;
  const float* p = src + ((size_t)b * 64 + d) * NPATCH;
  float s = 0.f;
  for (int i = 0; i < NPATCH; ++i) s += p[i];
  xc[t] = s * (1.0f / 225.0f);
  __syncthreads();
  if (t < 64) {
    float acc = 0.f;
    const float* w = fmg_w + t * 65;       // column 65*t of [128,4096]
    for (int c = 0; c < 128; ++c) acc += xc[c] * w[c * 4096];
    float sg = 1.0f / (1.0f + expf(-acc));
    sdfm[b * 64 + t] = sqrtf(sg);
  }
}

// ---- build X[2B,226,64] (+ pos) and Xn = LN1_0(X); one wave per row ----
__global__ void k_build(const float* __restrict__ hsi,
                        const float* __restrict__ cls_h, const float* __restrict__ cls_l,
                        const float* __restrict__ pos_h, const float* __restrict__ pos_l,
                        const float* __restrict__ g, const float* __restrict__ bb,
                        float* __restrict__ X, uint16_t* __restrict__ Xn) {
  int r = blockIdx.x;                 // sb*226 + n
  int sb = r / NTOK, n = r - sb * NTOK;
  int s = sb >> 6, b = sb & 63;
  int d = threadIdx.x;                // 64 threads = 1 wave
  float v;
  if (n == 0) v = s ? cls_l[d] : cls_h[d];
  else        v = hsi[((size_t)b * 64 + d) * NPATCH + (n - 1)];
  v += (s ? pos_l : pos_h)[n * ND + d];
  X[(size_t)r * ND + d] = v;
  float sm = v, sq = v * v;
  #pragma unroll
  for (int o = 32; o; o >>= 1) { sm += __shfl_xor(sm, o); sq += __shfl_xor(sq, o); }
  float m = sm * (1.f / 64.f);
  float rs = rsqrtf(sq * (1.f / 64.f) - m * m + 1e-5f);
  Xn[(size_t)r * ND + d] = f2b((v - m) * rs * g[d] + bb[d]);
}

// ---- weight convert+transpose to bf16 [col][k] layouts, all layers ----
__global__ __launch_bounds__(256) void k_wconv(
    const float* __restrict__ qkv_w, const float* __restrict__ out_w,
    const float* __restrict__ ff_w1, const float* __restrict__ ff_w2,
    uint16_t* __restrict__ Wqv, uint16_t* __restrict__ Wo,
    uint16_t* __restrict__ W1, uint16_t* __restrict__ W2) {
  int i = blockIdx.x * 256 + threadIdx.x;   // grid covers 524288
  if (i < 262144) {
    int ly = i >> 16, rem = i & 65535, n = rem >> 6, k = rem & 63;
    int col = n + ((n >> 9) << 9);          // n<512 ? q col n : v col n+512
    Wqv[i] = f2b(qkv_w[((size_t)ly * 64 + k) * 1536 + col]);
  } else if (i < 393216) {
    int j = i - 262144;
    int ly = j >> 15, rem = j & 32767, n = rem >> 9, k = rem & 511;
    Wo[j] = f2b(out_w[((size_t)ly * 512 + k) * 64 + n]);
  } else if (i < 458752) {
    int j = i - 393216;
    int ly = j >> 14, rem = j & 16383, n = rem >> 6, k = rem & 63;
    W1[j] = f2b(ff_w1[((size_t)ly * 64 + k) * 256 + n]);
  } else {
    int j = i - 458752;
    int ly = j >> 14, rem = j & 16383, n = rem >> 8, k = rem & 255;
    W2[j] = f2b(ff_w2[((size_t)ly * 256 + k) * 64 + n]);
  }
}

// ---- fused QV-projection + MFMA attention, swapped-operand QK^T ----
// QK^T computed as mfma(K_jt, Q_it): S[i][j] with i = lane&15 (lane-local row).
// Softmax fully per-lane (2+2 shfl_xor cross-quad). P -> A-frag transpose in
// registers: v_cvt_pk_bf16_f32 + v_permlane32_swap_b32 + shfl_xor(16) + selects.
// pb staging buffer eliminated. LDS = 30720 (qs) + 29760 (vt+pad) = 60480 B
// -> 2 blocks/CU -> 16 waves/CU; launch_bounds(512,4) pins VGPR<=128 for that.
__global__ __launch_bounds__(512, 4) void k_fattn(const uint16_t* __restrict__ Xn,
    const uint16_t* __restrict__ Wqv,   // [1024][64] this layer
    const float* __restrict__ sdfm, uint16_t* __restrict__ Og) {
  __shared__ __align__(16) uint16_t qs[240 * 64];
  __shared__ __align__(16) uint16_t vt[64 * VP + 32];
  int bh = blockIdx.x;
  int sb = bh >> 3, h = bh & 7;
  int t = threadIdx.x, w = t >> 6, l = t & 63;
  int quad = l >> 4, c = l & 15;
  const uint16_t* Xb = Xn + (size_t)sb * NTOK * ND;

  // zero the tail pad: chunk-7 PV B-reads run past row 63 into this region;
  // values multiply P==0 so they only need to be finite.
  if (t < 32) vt[64 * VP + t] = 0;

  float sf[4];
  #pragma unroll
  for (int dt = 0; dt < 4; ++dt)
    sf[dt] = sdfm[(sb & 63) * 64 + dt * 16 + c] * 0.35355339059327373f;  // sqrt(1/8)

  // phase 1: Q,V projection for this head (8-way wave split)
  for (int it = w; it < 15; it += 8) {
    int i0 = it * 16;
    int ri = i0 + c; if (ri > 225) ri = 225;
    bfrag8 a0 = *(const bfrag8*)(Xb + (size_t)ri * 64 + quad * 8);
    bfrag8 a1 = *(const bfrag8*)(Xb + (size_t)ri * 64 + 32 + quad * 8);
    #pragma unroll
    for (int dt = 0; dt < 4; ++dt) {
      int nq = h * 64 + dt * 16 + c;
      bfrag8 bq0 = *(const bfrag8*)(Wqv + (size_t)nq * 64 + quad * 8);
      bfrag8 bq1 = *(const bfrag8*)(Wqv + (size_t)nq * 64 + 32 + quad * 8);
      ffrag4 zq = {0.f, 0.f, 0.f, 0.f};
      zq = __builtin_amdgcn_mfma_f32_16x16x32_bf16(a0, bq0, zq, 0, 0, 0);
      zq = __builtin_amdgcn_mfma_f32_16x16x32_bf16(a1, bq1, zq, 0, 0, 0);
      bfrag8 bv0 = *(const bfrag8*)(Wqv + (size_t)(512 + nq) * 64 + quad * 8);
      bfrag8 bv1 = *(const bfrag8*)(Wqv + (size_t)(512 + nq) * 64 + 32 + quad * 8);
      ffrag4 zv = {0.f, 0.f, 0.f, 0.f};
      zv = __builtin_amdgcn_mfma_f32_16x16x32_bf16(a0, bv0, zv, 0, 0, 0);
      zv = __builtin_amdgcn_mfma_f32_16x16x32_bf16(a1, bv1, zv, 0, 0, 0);
      int d = dt * 16 + c;
      #pragma unroll
      for (int r = 0; r < 4; ++r) {
        int i = i0 + quad * 4 + r;
        qs[i * 64 + ((((d >> 3) ^ (i & 7))) << 3) + (d & 7)] = f2b(zq[r] * sf[dt]);
      }
      // packed V store: 4 consecutive i -> one b64 write (8B aligned: VP*2 % 8 == 0)
      int iv = i0 + quad * 4;
      if (iv + 3 < VP) {   // skip it=14,quad>=2 (would corrupt next d-row)
        unsigned lo = pk2(zv[0], zv[1]);
        unsigned hi = pk2(zv[2], zv[3]);
        *(unsigned long long*)(vt + (size_t)d * VP + iv) =
            ((unsigned long long)hi << 32) | lo;
      }
    }
  }
  __syncthreads();

  for (int it = w; it < 15; it += 8) {
    int i0 = it * 16;
    // B-frag = this i-tile's rows (i becomes the MFMA column -> lane-local)
    int rb = i0 + c, sk = rb & 7;
    bfrag8 b0 = *(const bfrag8*)(qs + rb * 64 + ((quad ^ sk) << 3));
    bfrag8 b1 = *(const bfrag8*)(qs + rb * 64 + (((quad + 4) ^ sk) << 3));
    ffrag4 acc[15];
    #pragma unroll
    for (int jt = 0; jt < 15; ++jt) {
      int ra = jt * 16 + c, sa = ra & 7;
      bfrag8 a0 = *(const bfrag8*)(qs + ra * 64 + ((quad ^ sa) << 3));
      bfrag8 a1 = *(const bfrag8*)(qs + ra * 64 + (((quad + 4) ^ sa) << 3));
      ffrag4 z = {0.f, 0.f, 0.f, 0.f};
      z = __builtin_amdgcn_mfma_f32_16x16x32_bf16(a0, b0, z, 0, 0, 0);
      z = __builtin_amdgcn_mfma_f32_16x16x32_bf16(a1, b1, z, 0, 0, 0);
      acc[jt] = z;   // acc[jt][r] = S[i0+c][jt*16 + quad*4 + r]
    }
    // mask invalid j (tile 14: j = 224 + quad*4 + r >= 226)
    #pragma unroll
    for (int r = 0; r < 4; ++r)
      if (quad * 4 + r >= 2) acc[14][r] = -1e30f;
    // softmax per lane: i = i0 + c fixed; reduce over (jt, r) in-reg, quads via shfl
    float m = -1e30f;
    #pragma unroll
    for (int jt = 0; jt < 15; ++jt)
      #pragma unroll
      for (int r = 0; r < 4; ++r) m = fmaxf(m, acc[jt][r]);
    m = fmaxf(m, __shfl_xor(m, 16));
    m = fmaxf(m, __shfl_xor(m, 32));
    float s = 0.f;
    #pragma unroll
    for (int jt = 0; jt < 15; ++jt)
      #pragma unroll
      for (int r = 0; r < 4; ++r) {
        float e = __expf(acc[jt][r] - m);
        acc[jt][r] = e;
        s += e;
      }
    s += __shfl_xor(s, 16);
    s += __shfl_xor(s, 32);
    float rinv = 1.f / s;

    ffrag4 oa[4];
    #pragma unroll
    for (int dt = 0; dt < 4; ++dt) oa[dt] = (ffrag4){0.f, 0.f, 0.f, 0.f};

    // PV: per 32-j chunk, build P A-frag in registers.
    // Target lane (c,q) needs P[i0+c][j = jj*32 + q*8 + s]; sources are the
    // cvt_pk'd acc pairs of quads {0..3} of tiles 2jj (XA*) and 2jj+1 (XB*).
    // permlane32_swap: Pa = {XA[0:31]|XB[0:31]}, Qa = {XA[32:63]|XB[32:63]};
    // then v0 = q&1 ? shfl16(Qa) : Pa ; v2 = q&1 ? Qa : shfl16(Pa) (ditto v1/v3).
    #pragma unroll
    for (int jj = 0; jj < 8; ++jj) {
      unsigned XA0 = pk2(acc[2 * jj][0], acc[2 * jj][1]);
      unsigned XA1 = pk2(acc[2 * jj][2], acc[2 * jj][3]);
      unsigned XB0 = 0, XB1 = 0;
      if (jj < 7) {                    // tile 15 does not exist -> P = 0
        XB0 = pk2(acc[2 * jj + 1][0], acc[2 * jj + 1][1]);
        XB1 = pk2(acc[2 * jj + 1][2], acc[2 * jj + 1][3]);
      }
      unsigned Pa = XA0, Qa = XB0, Pb = XA1, Qb = XB1;
      asm("v_permlane32_swap_b32 %0, %1" : "+v"(Pa), "+v"(Qa));
      asm("v_permlane32_swap_b32 %0, %1" : "+v"(Pb), "+v"(Qb));
      unsigned P0s = __shfl_xor(Pa, 16), Q0s = __shfl_xor(Qa, 16);
      unsigned P1s = __shfl_xor(Pb, 16), Q1s = __shfl_xor(Qb, 16);
      bool qlo = (quad & 1) == 0;
      union { unsigned u[4]; bfrag8 f; } pu;
      pu.u[0] = qlo ? Pa  : Q0s;
      pu.u[1] = qlo ? Pb  : Q1s;
      pu.u[2] = qlo ? P0s : Qa;
      pu.u[3] = qlo ? P1s : Qb;
      int j0 = jj * 32;
      #pragma unroll
      for (int dt = 0; dt < 4; ++dt) {
        bfrag8 vb = *(const bfrag8*)(vt + (dt * 16 + c) * VP + j0 + quad * 8);
        oa[dt] = __builtin_amdgcn_mfma_f32_16x16x32_bf16(pu.f, vb, oa[dt], 0, 0, 0);
      }
    }
    // broadcast 1/l to the C-layout rows (i = i0 + quad*4 + r)
    float rr[4];
    #pragma unroll
    for (int r = 0; r < 4; ++r) rr[r] = __shfl(rinv, quad * 4 + r);
    #pragma unroll
    for (int dt = 0; dt < 4; ++dt) {
      #pragma unroll
      for (int r = 0; r < 4; ++r) {
        int i = i0 + quad * 4 + r;
        if (i < NTOK)
          Og[((size_t)sb * NTOK + i) * NIN + h * DH + dt * 16 + c] =
              f2b(oa[dt][r] * rr[r]);
      }
    }
  }
}

// ---- merged proj+FF, one wave per 16-row tile (unchanged) ----
__global__ __launch_bounds__(64) void k_pf(const uint16_t* __restrict__ Og,
    const uint16_t* __restrict__ Wot,   // [64][512] bf16
    const float* __restrict__ bo, float* __restrict__ X,
    const float* __restrict__ g2, const float* __restrict__ bb2,
    const uint16_t* __restrict__ W1t,   // [256][64] bf16
    const float* __restrict__ b1,
    const uint16_t* __restrict__ W2t,   // [64][256] bf16
    const float* __restrict__ b2,
    const float* __restrict__ gn, const float* __restrict__ bbn,
    uint16_t* __restrict__ XnOut) {
  __shared__ __align__(16) uint16_t xa2[16 * 72];    // 2304 B
  __shared__ __align__(16) uint16_t ha[16 * 264];    // 8448 B
  int t = threadIdx.x;                 // 64 = 1 wave
  int quad = t >> 4, c = t & 15;
  int r0 = blockIdx.x * 16;

  // ---- proj part ----
  const uint16_t* orow = Og + (size_t)(r0 + c) * 512 + quad * 8;
  bfrag8 a[16];
  #pragma unroll
  for (int kc = 0; kc < 16; ++kc) a[kc] = *(const bfrag8*)(orow + kc * 32);
  ffrag4 acc[4];
  #pragma unroll
  for (int jt = 0; jt < 4; ++jt) acc[jt] = (ffrag4){0.f, 0.f, 0.f, 0.f};
  #pragma unroll
  for (int kc = 0; kc < 16; ++kc) {
    #pragma unroll
    for (int jt = 0; jt < 4; ++jt) {
      bfrag8 b = *(const bfrag8*)(Wot + (size_t)(jt * 16 + c) * 512 + kc * 32 + quad * 8);
      acc[jt] = __builtin_amdgcn_mfma_f32_16x16x32_bf16(a[kc], b, acc[jt], 0, 0, 0);
    }
  }
  float xv[4][4];
  #pragma unroll
  for (int jt = 0; jt < 4; ++jt) {
    float bv = bo[jt * 16 + c];
    #pragma unroll
    for (int r = 0; r < 4; ++r) {
      int il = quad * 4 + r;
      size_t idx = (size_t)(r0 + il) * 64 + jt * 16 + c;
      float v = X[idx] + acc[jt][r] + bv;
      X[idx] = v;
      xv[jt][r] = v;
    }
  }
  // LN2 -> xa2 (single wave; program-order LDS, no barrier)
  #pragma unroll
  for (int r = 0; r < 4; ++r) {
    float s = xv[0][r] + xv[1][r] + xv[2][r] + xv[3][r];
    float q = xv[0][r]*xv[0][r] + xv[1][r]*xv[1][r] + xv[2][r]*xv[2][r] + xv[3][r]*xv[3][r];
    #pragma unroll
    for (int o = 8; o; o >>= 1) { s += __shfl_xor(s, o); q += __shfl_xor(q, o); }
    float m = s * (1.f / 64.f);
    float rs = rsqrtf(q * (1.f / 64.f) - m * m + 1e-5f);
    int il = quad * 4 + r;
    #pragma unroll
    for (int jt = 0; jt < 4; ++jt) {
      int n = jt * 16 + c;
      xa2[il * 72 + n] = f2b((xv[jt][r] - m) * rs * g2[n] + bb2[n]);
    }
  }
  // ---- FF part ----
  const uint16_t* xrow = xa2 + c * 72;
  bfrag8 a0 = *(const bfrag8*)(xrow + quad * 8);
  bfrag8 a1 = *(const bfrag8*)(xrow + 32 + quad * 8);
  ffrag4 acc1[16];
  #pragma unroll
  for (int jt = 0; jt < 16; ++jt) {
    bfrag8 b0  = *(const bfrag8*)(W1t + (size_t)(jt * 16 + c) * 64 + quad * 8);
    bfrag8 b1f = *(const bfrag8*)(W1t + (size_t)(jt * 16 + c) * 64 + 32 + quad * 8);
    ffrag4 z = {0.f, 0.f, 0.f, 0.f};
    z = __builtin_amdgcn_mfma_f32_16x16x32_bf16(a0, b0, z, 0, 0, 0);
    z = __builtin_amdgcn_mfma_f32_16x16x32_bf16(a1, b1f, z, 0, 0, 0);
    acc1[jt] = z;
  }
  #pragma unroll
  for (int jt = 0; jt < 16; ++jt) {
    float bv = b1[jt * 16 + c];
    #pragma unroll
    for (int r = 0; r < 4; ++r) {
      float z = acc1[jt][r] + bv;
      float hg = 0.5f * z * (1.f + erff(z * 0.7071067811865476f));
      ha[(quad * 4 + r) * 264 + jt * 16 + c] = f2b(hg);
    }
  }
  ffrag4 o2[4];
  #pragma unroll
  for (int jt = 0; jt < 4; ++jt) o2[jt] = (ffrag4){0.f, 0.f, 0.f, 0.f};
  #pragma unroll
  for (int kc = 0; kc < 8; ++kc) {
    bfrag8 pa = *(const bfrag8*)(ha + c * 264 + kc * 32 + quad * 8);
    #pragma unroll
    for (int jt = 0; jt < 4; ++jt) {
      bfrag8 vb = *(const bfrag8*)(W2t + (size_t)(jt * 16 + c) * 256 + kc * 32 + quad * 8);
      o2[jt] = __builtin_amdgcn_mfma_f32_16x16x32_bf16(pa, vb, o2[jt], 0, 0, 0);
    }
  }
  float yv[4][4];
  #pragma unroll
  for (int jt = 0; jt < 4; ++jt) {
    float bv = b2[jt * 16 + c];
    #pragma unroll
    for (int r = 0; r < 4; ++r) {
      int il = quad * 4 + r;
      size_t idx = (size_t)(r0 + il) * 64 + jt * 16 + c;
      float v = X[idx] + o2[jt][r] + bv;
      X[idx] = v;
      yv[jt][r] = v;
    }
  }
  #pragma unroll
  for (int r = 0; r < 4; ++r) {
    float s = yv[0][r] + yv[1][r] + yv[2][r] + yv[3][r];
    float q = yv[0][r]*yv[0][r] + yv[1][r]*yv[1][r] + yv[2][r]*yv[2][r] + yv[3][r]*yv[3][r];
    #pragma unroll
    for (int o = 8; o; o >>= 1) { s += __shfl_xor(s, o); q += __shfl_xor(q, o); }
    float m = s * (1.f / 64.f);
    float rs = rsqrtf(q * (1.f / 64.f) - m * m + 1e-5f);
    int il = quad * 4 + r;
    #pragma unroll
    for (int jt = 0; jt < 4; ++jt) {
      int n = jt * 16 + c;
      XnOut[(size_t)(r0 + il) * 64 + n] = f2b((yv[jt][r] - m) * rs * gn[n] + bbn[n]);
    }
  }
}

// ---- swap cls tokens between streams; refresh Xn (LN1 layer0) for those rows ----
__global__ void k_xchg(float* __restrict__ X, uint16_t* __restrict__ Xn,
                       const float* __restrict__ g, const float* __restrict__ bb) {
  int b = blockIdx.x, d = threadIdx.x;   // 64 blocks x 64 threads (1 wave)
  size_t i0 = (size_t)(b * NTOK) * ND + d;
  size_t i1 = (size_t)((64 + b) * NTOK) * ND + d;
  float a = X[i0], cc = X[i1];
  X[i0] = cc; X[i1] = a;
  float s0 = cc, q0 = cc * cc, s1 = a, q1 = a * a;
  #pragma unroll
  for (int o = 32; o; o >>= 1) {
    s0 += __shfl_xor(s0, o); q0 += __shfl_xor(q0, o);
    s1 += __shfl_xor(s1, o); q1 += __shfl_xor(q1, o);
  }
  float m0 = s0 * (1.f / 64.f), rs0 = rsqrtf(q0 * (1.f / 64.f) - m0 * m0 + 1e-5f);
  float m1 = s1 * (1.f / 64.f), rs1 = rsqrtf(q1 * (1.f / 64.f) - m1 * m1 + 1e-5f);
  Xn[i0] = f2b((cc - m0) * rs0 * g[d] + bb[d]);
  Xn[i1] = f2b((a - m1) * rs1 * g[d] + bb[d]);
}

// ---- final: out = h_cls + l_cls ----
__global__ void k_out(const float* __restrict__ X, float* __restrict__ out) {
  int i = blockIdx.x * 64 + threadIdx.x;
  int b = i >> 6, d = i & 63;
  out[i] = X[(size_t)b * NTOK * ND + d] + X[(size_t)(64 + b) * NTOK * ND + d];
}

extern "C" void kernel_launch(void* const* d_in, const int* in_sizes, int n_in,
                              void* d_out, int out_size, void* d_ws, size_t ws_size,
                              hipStream_t stream) {
  const float* hsi   = (const float*)d_in[0];
  const float* lidar = (const float*)d_in[1];
  const float* cls_h = (const float*)d_in[2];
  const float* cls_l = (const float*)d_in[3];
  const float* pos_h = (const float*)d_in[4];
  const float* pos_l = (const float*)d_in[5];
  const float* fmg_w = (const float*)d_in[6];
  const float* ln1_g = (const float*)d_in[7];
  const float* ln1_b = (const float*)d_in[8];
  const float* qkv_w = (const float*)d_in[9];
  const float* out_w = (const float*)d_in[10];
  const float* out_b = (const float*)d_in[11];
  const float* ln2_g = (const float*)d_in[12];
  const float* ln2_b = (const float*)d_in[13];
  const float* ff_w1 = (const float*)d_in[14];
  const float* ff_b1 = (const float*)d_in[15];
  const float* ff_w2 = (const float*)d_in[16];
  const float* ff_b2 = (const float*)d_in[17];

  char* ws = (char*)d_ws;
  float*    X    = (float*)ws;                       // 7,405,568 B
  float*    sdfm = (float*)(ws + 7405568);           // 16,384 B
  uint16_t* Xn   = (uint16_t*)(ws + 7421952);        // 3,702,784 B
  uint16_t* Og   = (uint16_t*)(ws + 11124736);       // 29,622,272 B
  uint16_t* Wqv  = (uint16_t*)(ws + 40747008);       // 524,288 B
  uint16_t* Wo   = (uint16_t*)(ws + 41271296);       // 262,144 B
  uint16_t* W1   = (uint16_t*)(ws + 41533440);       // 131,072 B
  uint16_t* W2   = (uint16_t*)(ws + 41664512);       // 131,072 B -> end 41,795,584

  k_wconv<<<2048, 256, 0, stream>>>(qkv_w, out_w, ff_w1, ff_w2, Wqv, Wo, W1, W2);
  k_dfm<<<NB, 128, 0, stream>>>(hsi, lidar, fmg_w, sdfm);
  k_build<<<NROWS, 64, 0, stream>>>(hsi, cls_h, cls_l, pos_h, pos_l,
                                    ln1_g, ln1_b, X, Xn);
  for (int pass = 0; pass < 2; ++pass) {
    for (int ly = 0; ly < NDEPTH; ++ly) {
      int nx = (ly + 1) & 3;   // next layer's LN1 params (harmless on final layer)
      k_fattn<<<NSB * NH, 512, 0, stream>>>(Xn, Wqv + (size_t)ly * 65536, sdfm, Og);
      k_pf<<<NROWS / 16, 64, 0, stream>>>(Og, Wo + (size_t)ly * 32768, out_b + ly * ND,
                                          X, ln2_g + ly * ND, ln2_b + ly * ND,
                                          W1 + (size_t)ly * 16384, ff_b1 + ly * NMLP,
                                          W2 + (size_t)ly * 16384, ff_b2 + ly * ND,
                                          ln1_g + nx * ND, ln1_b + nx * ND, Xn);
    }
    if (pass == 0) k_xchg<<<64, 64, 0, stream>>>(X, Xn, ln1_g, ln1_b);
  }
  k_out<<<64, 64, 0, stream>>>(X, (float*)d_out);
}

// Round 2
// 906.384 us; speedup vs baseline: 1.5169x; 1.5169x over previous
//
#include <hip/hip_runtime.h>
#include <hip/hip_bf16.h>
#include <cstdint>

#define NB 64        // batch
#define ND 64        // DIM
#define NH 8         // heads
#define DH 64        // dim_head
#define NIN 512      // inner
#define NMLP 256
#define NDEPTH 4
#define NPATCH 225
#define NTOK 226
#define NSB 128      // 2*B (both streams batched)
#define NROWS (NSB*NTOK)   // 28928

#define VP 232       // attention Vt LDS pitch (bf16 units); 232=8*29 keeps rows 16B-aligned,
                     // dword row-stride 116 ≡ 20 (mod 32) -> ~2-way banks (vs 24 @ VP=240)

typedef __attribute__((ext_vector_type(8))) short bfrag8;
typedef __attribute__((ext_vector_type(4))) float ffrag4;

// RNE bf16: bit-exact vs __float2bfloat16 for finite inputs, 3 VALU ops.
__device__ __forceinline__ unsigned short f2b(float f) {
  uint32_t u; __builtin_memcpy(&u, &f, 4);
  u += 0x7fff + ((u >> 16) & 1);
  return (unsigned short)(u >> 16);
}

// pack 2 f32 -> 2 bf16 in one u32 (lo = first arg), RNE — single VALU op
__device__ __forceinline__ unsigned pk2(float lo, float hi) {
  unsigned r;
  asm("v_cvt_pk_bf16_f32 %0, %1, %2" : "=v"(r) : "v"(lo), "v"(hi));
  return r;
}

// ---- fusion-matrix diagonal: sdfm[b][d] = sqrt(sigmoid(x @ fmg_w[:,65d])) ----
__global__ void k_dfm(const float* __restrict__ hsi, const float* __restrict__ lidar,
                      const float* __restrict__ fmg_w, float* __restrict__ sdfm) {
  __shared__ float xc[128];
  int b = blockIdx.x, t = threadIdx.x;
  const float* src = (t < 64) ? hsi : lidar;
  int d = t & 63;
  const float* p = src + ((size_t)b * 64 + d) * NPATCH;
  float s = 0.f;
  for (int i = 0; i < NPATCH; ++i) s += p[i];
  xc[t] = s * (1.0f / 225.0f);
  __syncthreads();
  if (t < 64) {
    float acc = 0.f;
    const float* w = fmg_w + t * 65;       // column 65*t of [128,4096]
    for (int c = 0; c < 128; ++c) acc += xc[c] * w[c * 4096];
    float sg = 1.0f / (1.0f + expf(-acc));
    sdfm[b * 64 + t] = sqrtf(sg);
  }
}

// ---- build X[2B,226,64] (+ pos) and Xn = LN1_0(X); one wave per row ----
__global__ void k_build(const float* __restrict__ hsi,
                        const float* __restrict__ cls_h, const float* __restrict__ cls_l,
                        const float* __restrict__ pos_h, const float* __restrict__ pos_l,
                        const float* __restrict__ g, const float* __restrict__ bb,
                        float* __restrict__ X, uint16_t* __restrict__ Xn) {
  int r = blockIdx.x;                 // sb*226 + n
  int sb = r / NTOK, n = r - sb * NTOK;
  int s = sb >> 6, b = sb & 63;
  int d = threadIdx.x;                // 64 threads = 1 wave
  float v;
  if (n == 0) v = s ? cls_l[d] : cls_h[d];
  else        v = hsi[((size_t)b * 64 + d) * NPATCH + (n - 1)];
  v += (s ? pos_l : pos_h)[n * ND + d];
  X[(size_t)r * ND + d] = v;
  float sm = v, sq = v * v;
  #pragma unroll
  for (int o = 32; o; o >>= 1) { sm += __shfl_xor(sm, o); sq += __shfl_xor(sq, o); }
  float m = sm * (1.f / 64.f);
  float rs = rsqrtf(sq * (1.f / 64.f) - m * m + 1e-5f);
  Xn[(size_t)r * ND + d] = f2b((v - m) * rs * g[d] + bb[d]);
}

// ---- weight convert+transpose to bf16 [col][k] layouts, all layers ----
__global__ __launch_bounds__(256) void k_wconv(
    const float* __restrict__ qkv_w, const float* __restrict__ out_w,
    const float* __restrict__ ff_w1, const float* __restrict__ ff_w2,
    uint16_t* __restrict__ Wqv, uint16_t* __restrict__ Wo,
    uint16_t* __restrict__ W1, uint16_t* __restrict__ W2) {
  int i = blockIdx.x * 256 + threadIdx.x;   // grid covers 524288
  if (i < 262144) {
    int ly = i >> 16, rem = i & 65535, n = rem >> 6, k = rem & 63;
    int col = n + ((n >> 9) << 9);          // n<512 ? q col n : v col n+512
    Wqv[i] = f2b(qkv_w[((size_t)ly * 64 + k) * 1536 + col]);
  } else if (i < 393216) {
    int j = i - 262144;
    int ly = j >> 15, rem = j & 32767, n = rem >> 9, k = rem & 511;
    Wo[j] = f2b(out_w[((size_t)ly * 512 + k) * 64 + n]);
  } else if (i < 458752) {
    int j = i - 393216;
    int ly = j >> 14, rem = j & 16383, n = rem >> 6, k = rem & 63;
    W1[j] = f2b(ff_w1[((size_t)ly * 64 + k) * 256 + n]);
  } else {
    int j = i - 458752;
    int ly = j >> 14, rem = j & 16383, n = rem >> 8, k = rem & 255;
    W2[j] = f2b(ff_w2[((size_t)ly * 256 + k) * 64 + n]);
  }
}

// ---- fused QV-projection + MFMA attention, swapped-operand QK^T ----
// QK^T computed as mfma(K_jt, Q_it): S[i][j] with i = lane&15 (lane-local row).
// Softmax fully per-lane (2+2 shfl_xor cross-quad). P -> A-frag transpose in
// registers: v_cvt_pk_bf16_f32 + v_permlane32_swap_b32 + shfl_xor(16) + selects.
// NO min-waves pledge: __launch_bounds__(512,4) capped unified VGPR+AGPR at 128
// and spilled acc[15] to scratch (R1: FETCH 200MB/dispatch). Plain (512) lets the
// compiler use the AGPR file for accumulators with zero spill (R0: 56 VGPR).
// E is packed to bf16 pairs inside the exp loop so the f32 acc dies early.
__global__ __launch_bounds__(512) void k_fattn(const uint16_t* __restrict__ Xn,
    const uint16_t* __restrict__ Wqv,   // [1024][64] this layer
    const float* __restrict__ sdfm, uint16_t* __restrict__ Og) {
  __shared__ __align__(16) uint16_t qs[240 * 64];
  __shared__ __align__(16) uint16_t vt[64 * VP + 32];
  int bh = blockIdx.x;
  int sb = bh >> 3, h = bh & 7;
  int t = threadIdx.x, w = t >> 6, l = t & 63;
  int quad = l >> 4, c = l & 15;
  const uint16_t* Xb = Xn + (size_t)sb * NTOK * ND;

  // zero the tail pad: chunk-7 PV B-reads run past row 63 into this region;
  // values multiply P==0 so they only need to be finite.
  if (t < 32) vt[64 * VP + t] = 0;

  float sf[4];
  #pragma unroll
  for (int dt = 0; dt < 4; ++dt)
    sf[dt] = sdfm[(sb & 63) * 64 + dt * 16 + c] * 0.35355339059327373f;  // sqrt(1/8)

  // phase 1: Q,V projection for this head (8-way wave split)
  for (int it = w; it < 15; it += 8) {
    int i0 = it * 16;
    int ri = i0 + c; if (ri > 225) ri = 225;
    bfrag8 a0 = *(const bfrag8*)(Xb + (size_t)ri * 64 + quad * 8);
    bfrag8 a1 = *(const bfrag8*)(Xb + (size_t)ri * 64 + 32 + quad * 8);
    #pragma unroll
    for (int dt = 0; dt < 4; ++dt) {
      int nq = h * 64 + dt * 16 + c;
      bfrag8 bq0 = *(const bfrag8*)(Wqv + (size_t)nq * 64 + quad * 8);
      bfrag8 bq1 = *(const bfrag8*)(Wqv + (size_t)nq * 64 + 32 + quad * 8);
      ffrag4 zq = {0.f, 0.f, 0.f, 0.f};
      zq = __builtin_amdgcn_mfma_f32_16x16x32_bf16(a0, bq0, zq, 0, 0, 0);
      zq = __builtin_amdgcn_mfma_f32_16x16x32_bf16(a1, bq1, zq, 0, 0, 0);
      bfrag8 bv0 = *(const bfrag8*)(Wqv + (size_t)(512 + nq) * 64 + quad * 8);
      bfrag8 bv1 = *(const bfrag8*)(Wqv + (size_t)(512 + nq) * 64 + 32 + quad * 8);
      ffrag4 zv = {0.f, 0.f, 0.f, 0.f};
      zv = __builtin_amdgcn_mfma_f32_16x16x32_bf16(a0, bv0, zv, 0, 0, 0);
      zv = __builtin_amdgcn_mfma_f32_16x16x32_bf16(a1, bv1, zv, 0, 0, 0);
      int d = dt * 16 + c;
      #pragma unroll
      for (int r = 0; r < 4; ++r) {
        int i = i0 + quad * 4 + r;
        qs[i * 64 + ((((d >> 3) ^ (i & 7))) << 3) + (d & 7)] = f2b(zq[r] * sf[dt]);
      }
      // packed V store: 4 consecutive i -> one b64 write (8B aligned: VP*2 % 8 == 0)
      int iv = i0 + quad * 4;
      if (iv + 3 < VP) {   // skip it=14,quad>=2 (would corrupt next d-row)
        unsigned lo = pk2(zv[0], zv[1]);
        unsigned hi = pk2(zv[2], zv[3]);
        *(unsigned long long*)(vt + (size_t)d * VP + iv) =
            ((unsigned long long)hi << 32) | lo;
      }
    }
  }
  __syncthreads();

  for (int it = w; it < 15; it += 8) {
    int i0 = it * 16;
    // B-frag = this i-tile's rows (i becomes the MFMA column -> lane-local)
    int rb = i0 + c, sk = rb & 7;
    bfrag8 b0 = *(const bfrag8*)(qs + rb * 64 + ((quad ^ sk) << 3));
    bfrag8 b1 = *(const bfrag8*)(qs + rb * 64 + (((quad + 4) ^ sk) << 3));
    ffrag4 acc[15];
    #pragma unroll
    for (int jt = 0; jt < 15; ++jt) {
      int ra = jt * 16 + c, sa = ra & 7;
      bfrag8 a0 = *(const bfrag8*)(qs + ra * 64 + ((quad ^ sa) << 3));
      bfrag8 a1 = *(const bfrag8*)(qs + ra * 64 + (((quad + 4) ^ sa) << 3));
      ffrag4 z = {0.f, 0.f, 0.f, 0.f};
      z = __builtin_amdgcn_mfma_f32_16x16x32_bf16(a0, b0, z, 0, 0, 0);
      z = __builtin_amdgcn_mfma_f32_16x16x32_bf16(a1, b1, z, 0, 0, 0);
      acc[jt] = z;   // acc[jt][r] = S[i0+c][jt*16 + quad*4 + r]
    }
    // mask invalid j (tile 14: j = 224 + quad*4 + r >= 226)
    #pragma unroll
    for (int r = 0; r < 4; ++r)
      if (quad * 4 + r >= 2) acc[14][r] = -1e30f;
    // softmax per lane: i = i0 + c fixed; reduce over (jt, r) in-reg, quads via shfl
    float m = -1e30f;
    #pragma unroll
    for (int jt = 0; jt < 15; ++jt)
      #pragma unroll
      for (int r = 0; r < 4; ++r) m = fmaxf(m, acc[jt][r]);
    m = fmaxf(m, __shfl_xor(m, 16));
    m = fmaxf(m, __shfl_xor(m, 32));
    // exp + sum + pack-to-bf16 in one pass: f32 acc dies here, halving the
    // post-softmax live set (pk = 30 u32 vs 60 f32).
    float s = 0.f;
    unsigned pk[15][2];
    #pragma unroll
    for (int jt = 0; jt < 15; ++jt) {
      float e0 = __expf(acc[jt][0] - m);
      float e1 = __expf(acc[jt][1] - m);
      float e2 = __expf(acc[jt][2] - m);
      float e3 = __expf(acc[jt][3] - m);
      s += (e0 + e1) + (e2 + e3);
      pk[jt][0] = pk2(e0, e1);
      pk[jt][1] = pk2(e2, e3);
    }
    s += __shfl_xor(s, 16);
    s += __shfl_xor(s, 32);
    float rinv = 1.f / s;

    ffrag4 oa[4];
    #pragma unroll
    for (int dt = 0; dt < 4; ++dt) oa[dt] = (ffrag4){0.f, 0.f, 0.f, 0.f};

    // PV: per 32-j chunk, build P A-frag in registers.
    // Target lane (c,q) needs P[i0+c][j = jj*32 + q*8 + s]; sources are the
    // packed acc pairs of quads {0..3} of tiles 2jj (XA*) and 2jj+1 (XB*).
    // permlane32_swap: Pa = {XA[0:31]|XB[0:31]}, Qa = {XA[32:63]|XB[32:63]};
    // then v0 = q&1 ? shfl16(Qa) : Pa ; v2 = q&1 ? Qa : shfl16(Pa) (ditto v1/v3).
    #pragma unroll
    for (int jj = 0; jj < 8; ++jj) {
      unsigned XA0 = pk[2 * jj][0];
      unsigned XA1 = pk[2 * jj][1];
      unsigned XB0 = 0, XB1 = 0;
      if (jj < 7) {                    // tile 15 does not exist -> P = 0
        XB0 = pk[2 * jj + 1][0];
        XB1 = pk[2 * jj + 1][1];
      }
      unsigned Pa = XA0, Qa = XB0, Pb = XA1, Qb = XB1;
      asm("v_permlane32_swap_b32 %0, %1" : "+v"(Pa), "+v"(Qa));
      asm("v_permlane32_swap_b32 %0, %1" : "+v"(Pb), "+v"(Qb));
      unsigned P0s = __shfl_xor(Pa, 16), Q0s = __shfl_xor(Qa, 16);
      unsigned P1s = __shfl_xor(Pb, 16), Q1s = __shfl_xor(Qb, 16);
      bool qlo = (quad & 1) == 0;
      union { unsigned u[4]; bfrag8 f; } pu;
      pu.u[0] = qlo ? Pa  : Q0s;
      pu.u[1] = qlo ? Pb  : Q1s;
      pu.u[2] = qlo ? P0s : Qa;
      pu.u[3] = qlo ? P1s : Qb;
      int j0 = jj * 32;
      #pragma unroll
      for (int dt = 0; dt < 4; ++dt) {
        bfrag8 vb = *(const bfrag8*)(vt + (dt * 16 + c) * VP + j0 + quad * 8);
        oa[dt] = __builtin_amdgcn_mfma_f32_16x16x32_bf16(pu.f, vb, oa[dt], 0, 0, 0);
      }
    }
    // broadcast 1/l to the C-layout rows (i = i0 + quad*4 + r)
    float rr[4];
    #pragma unroll
    for (int r = 0; r < 4; ++r) rr[r] = __shfl(rinv, quad * 4 + r);
    #pragma unroll
    for (int dt = 0; dt < 4; ++dt) {
      #pragma unroll
      for (int r = 0; r < 4; ++r) {
        int i = i0 + quad * 4 + r;
        if (i < NTOK)
          Og[((size_t)sb * NTOK + i) * NIN + h * DH + dt * 16 + c] =
              f2b(oa[dt][r] * rr[r]);
      }
    }
  }
}

// ---- merged proj+FF, one wave per 16-row tile (unchanged) ----
__global__ __launch_bounds__(64) void k_pf(const uint16_t* __restrict__ Og,
    const uint16_t* __restrict__ Wot,   // [64][512] bf16
    const float* __restrict__ bo, float* __restrict__ X,
    const float* __restrict__ g2, const float* __restrict__ bb2,
    const uint16_t* __restrict__ W1t,   // [256][64] bf16
    const float* __restrict__ b1,
    const uint16_t* __restrict__ W2t,   // [64][256] bf16
    const float* __restrict__ b2,
    const float* __restrict__ gn, const float* __restrict__ bbn,
    uint16_t* __restrict__ XnOut) {
  __shared__ __align__(16) uint16_t xa2[16 * 72];    // 2304 B
  __shared__ __align__(16) uint16_t ha[16 * 264];    // 8448 B
  int t = threadIdx.x;                 // 64 = 1 wave
  int quad = t >> 4, c = t & 15;
  int r0 = blockIdx.x * 16;

  // ---- proj part ----
  const uint16_t* orow = Og + (size_t)(r0 + c) * 512 + quad * 8;
  bfrag8 a[16];
  #pragma unroll
  for (int kc = 0; kc < 16; ++kc) a[kc] = *(const bfrag8*)(orow + kc * 32);
  ffrag4 acc[4];
  #pragma unroll
  for (int jt = 0; jt < 4; ++jt) acc[jt] = (ffrag4){0.f, 0.f, 0.f, 0.f};
  #pragma unroll
  for (int kc = 0; kc < 16; ++kc) {
    #pragma unroll
    for (int jt = 0; jt < 4; ++jt) {
      bfrag8 b = *(const bfrag8*)(Wot + (size_t)(jt * 16 + c) * 512 + kc * 32 + quad * 8);
      acc[jt] = __builtin_amdgcn_mfma_f32_16x16x32_bf16(a[kc], b, acc[jt], 0, 0, 0);
    }
  }
  float xv[4][4];
  #pragma unroll
  for (int jt = 0; jt < 4; ++jt) {
    float bv = bo[jt * 16 + c];
    #pragma unroll
    for (int r = 0; r < 4; ++r) {
      int il = quad * 4 + r;
      size_t idx = (size_t)(r0 + il) * 64 + jt * 16 + c;
      float v = X[idx] + acc[jt][r] + bv;
      X[idx] = v;
      xv[jt][r] = v;
    }
  }
  // LN2 -> xa2 (single wave; program-order LDS, no barrier)
  #pragma unroll
  for (int r = 0; r < 4; ++r) {
    float s = xv[0][r] + xv[1][r] + xv[2][r] + xv[3][r];
    float q = xv[0][r]*xv[0][r] + xv[1][r]*xv[1][r] + xv[2][r]*xv[2][r] + xv[3][r]*xv[3][r];
    #pragma unroll
    for (int o = 8; o; o >>= 1) { s += __shfl_xor(s, o); q += __shfl_xor(q, o); }
    float m = s * (1.f / 64.f);
    float rs = rsqrtf(q * (1.f / 64.f) - m * m + 1e-5f);
    int il = quad * 4 + r;
    #pragma unroll
    for (int jt = 0; jt < 4; ++jt) {
      int n = jt * 16 + c;
      xa2[il * 72 + n] = f2b((xv[jt][r] - m) * rs * g2[n] + bb2[n]);
    }
  }
  // ---- FF part ----
  const uint16_t* xrow = xa2 + c * 72;
  bfrag8 a0 = *(const bfrag8*)(xrow + quad * 8);
  bfrag8 a1 = *(const bfrag8*)(xrow + 32 + quad * 8);
  ffrag4 acc1[16];
  #pragma unroll
  for (int jt = 0; jt < 16; ++jt) {
    bfrag8 b0  = *(const bfrag8*)(W1t + (size_t)(jt * 16 + c) * 64 + quad * 8);
    bfrag8 b1f = *(const bfrag8*)(W1t + (size_t)(jt * 16 + c) * 64 + 32 + quad * 8);
    ffrag4 z = {0.f, 0.f, 0.f, 0.f};
    z = __builtin_amdgcn_mfma_f32_16x16x32_bf16(a0, b0, z, 0, 0, 0);
    z = __builtin_amdgcn_mfma_f32_16x16x32_bf16(a1, b1f, z, 0, 0, 0);
    acc1[jt] = z;
  }
  #pragma unroll
  for (int jt = 0; jt < 16; ++jt) {
    float bv = b1[jt * 16 + c];
    #pragma unroll
    for (int r = 0; r < 4; ++r) {
      float z = acc1[jt][r] + bv;
      float hg = 0.5f * z * (1.f + erff(z * 0.7071067811865476f));
      ha[(quad * 4 + r) * 264 + jt * 16 + c] = f2b(hg);
    }
  }
  ffrag4 o2[4];
  #pragma unroll
  for (int jt = 0; jt < 4; ++jt) o2[jt] = (ffrag4){0.f, 0.f, 0.f, 0.f};
  #pragma unroll
  for (int kc = 0; kc < 8; ++kc) {
    bfrag8 pa = *(const bfrag8*)(ha + c * 264 + kc * 32 + quad * 8);
    #pragma unroll
    for (int jt = 0; jt < 4; ++jt) {
      bfrag8 vb = *(const bfrag8*)(W2t + (size_t)(jt * 16 + c) * 256 + kc * 32 + quad * 8);
      o2[jt] = __builtin_amdgcn_mfma_f32_16x16x32_bf16(pa, vb, o2[jt], 0, 0, 0);
    }
  }
  float yv[4][4];
  #pragma unroll
  for (int jt = 0; jt < 4; ++jt) {
    float bv = b2[jt * 16 + c];
    #pragma unroll
    for (int r = 0; r < 4; ++r) {
      int il = quad * 4 + r;
      size_t idx = (size_t)(r0 + il) * 64 + jt * 16 + c;
      float v = X[idx] + o2[jt][r] + bv;
      X[idx] = v;
      yv[jt][r] = v;
    }
  }
  #pragma unroll
  for (int r = 0; r < 4; ++r) {
    float s = yv[0][r] + yv[1][r] + yv[2][r] + yv[3][r];
    float q = yv[0][r]*yv[0][r] + yv[1][r]*yv[1][r] + yv[2][r]*yv[2][r] + yv[3][r]*yv[3][r];
    #pragma unroll
    for (int o = 8; o; o >>= 1) { s += __shfl_xor(s, o); q += __shfl_xor(q, o); }
    float m = s * (1.f / 64.f);
    float rs = rsqrtf(q * (1.f / 64.f) - m * m + 1e-5f);
    int il = quad * 4 + r;
    #pragma unroll
    for (int jt = 0; jt < 4; ++jt) {
      int n = jt * 16 + c;
      XnOut[(size_t)(r0 + il) * 64 + n] = f2b((yv[jt][r] - m) * rs * gn[n] + bbn[n]);
    }
  }
}

// ---- swap cls tokens between streams; refresh Xn (LN1 layer0) for those rows ----
__global__ void k_xchg(float* __restrict__ X, uint16_t* __restrict__ Xn,
                       const float* __restrict__ g, const float* __restrict__ bb) {
  int b = blockIdx.x, d = threadIdx.x;   // 64 blocks x 64 threads (1 wave)
  size_t i0 = (size_t)(b * NTOK) * ND + d;
  size_t i1 = (size_t)((64 + b) * NTOK) * ND + d;
  float a = X[i0], cc = X[i1];
  X[i0] = cc; X[i1] = a;
  float s0 = cc, q0 = cc * cc, s1 = a, q1 = a * a;
  #pragma unroll
  for (int o = 32; o; o >>= 1) {
    s0 += __shfl_xor(s0, o); q0 += __shfl_xor(q0, o);
    s1 += __shfl_xor(s1, o); q1 += __shfl_xor(q1, o);
  }
  float m0 = s0 * (1.f / 64.f), rs0 = rsqrtf(q0 * (1.f / 64.f) - m0 * m0 + 1e-5f);
  float m1 = s1 * (1.f / 64.f), rs1 = rsqrtf(q1 * (1.f / 64.f) - m1 * m1 + 1e-5f);
  Xn[i0] = f2b((cc - m0) * rs0 * g[d] + bb[d]);
  Xn[i1] = f2b((a - m1) * rs1 * g[d] + bb[d]);
}

// ---- final: out = h_cls + l_cls ----
__global__ void k_out(const float* __restrict__ X, float* __restrict__ out) {
  int i = blockIdx.x * 64 + threadIdx.x;
  int b = i >> 6, d = i & 63;
  out[i] = X[(size_t)b * NTOK * ND + d] + X[(size_t)(64 + b) * NTOK * ND + d];
}

extern "C" void kernel_launch(void* const* d_in, const int* in_sizes, int n_in,
                              void* d_out, int out_size, void* d_ws, size_t ws_size,
                              hipStream_t stream) {
  const float* hsi   = (const float*)d_in[0];
  const float* lidar = (const float*)d_in[1];
  const float* cls_h = (const float*)d_in[2];
  const float* cls_l = (const float*)d_in[3];
  const float* pos_h = (const float*)d_in[4];
  const float* pos_l = (const float*)d_in[5];
  const float* fmg_w = (const float*)d_in[6];
  const float* ln1_g = (const float*)d_in[7];
  const float* ln1_b = (const float*)d_in[8];
  const float* qkv_w = (const float*)d_in[9];
  const float* out_w = (const float*)d_in[10];
  const float* out_b = (const float*)d_in[11];
  const float* ln2_g = (const float*)d_in[12];
  const float* ln2_b = (const float*)d_in[13];
  const float* ff_w1 = (const float*)d_in[14];
  const float* ff_b1 = (const float*)d_in[15];
  const float* ff_w2 = (const float*)d_in[16];
  const float* ff_b2 = (const float*)d_in[17];

  char* ws = (char*)d_ws;
  float*    X    = (float*)ws;                       // 7,405,568 B
  float*    sdfm = (float*)(ws + 7405568);           // 16,384 B
  uint16_t* Xn   = (uint16_t*)(ws + 7421952);        // 3,702,784 B
  uint16_t* Og   = (uint16_t*)(ws + 11124736);       // 29,622,272 B
  uint16_t* Wqv  = (uint16_t*)(ws + 40747008);       // 524,288 B
  uint16_t* Wo   = (uint16_t*)(ws + 41271296);       // 262,144 B
  uint16_t* W1   = (uint16_t*)(ws + 41533440);       // 131,072 B
  uint16_t* W2   = (uint16_t*)(ws + 41664512);       // 131,072 B -> end 41,795,584

  k_wconv<<<2048, 256, 0, stream>>>(qkv_w, out_w, ff_w1, ff_w2, Wqv, Wo, W1, W2);
  k_dfm<<<NB, 128, 0, stream>>>(hsi, lidar, fmg_w, sdfm);
  k_build<<<NROWS, 64, 0, stream>>>(hsi, cls_h, cls_l, pos_h, pos_l,
                                    ln1_g, ln1_b, X, Xn);
  for (int pass = 0; pass < 2; ++pass) {
    for (int ly = 0; ly < NDEPTH; ++ly) {
      int nx = (ly + 1) & 3;   // next layer's LN1 params (harmless on final layer)
      k_fattn<<<NSB * NH, 512, 0, stream>>>(Xn, Wqv + (size_t)ly * 65536, sdfm, Og);
      k_pf<<<NROWS / 16, 64, 0, stream>>>(Og, Wo + (size_t)ly * 32768, out_b + ly * ND,
                                          X, ln2_g + ly * ND, ln2_b + ly * ND,
                                          W1 + (size_t)ly * 16384, ff_b1 + ly * NMLP,
                                          W2 + (size_t)ly * 16384, ff_b2 + ly * ND,
                                          ln1_g + nx * ND, ln1_b + nx * ND, Xn);
    }
    if (pass == 0) k_xchg<<<64, 64, 0, stream>>>(X, Xn, ln1_g, ln1_b);
  }
  k_out<<<64, 64, 0, stream>>>(X, (float*)d_out);
}

// Round 3
// 889.129 us; speedup vs baseline: 1.5463x; 1.0194x over previous
//
#include <hip/hip_runtime.h>
#include <hip/hip_bf16.h>
#include <cstdint>

#define NB 64        // batch
#define ND 64        // DIM
#define NH 8         // heads
#define DH 64        // dim_head
#define NIN 512      // inner
#define NMLP 256
#define NDEPTH 4
#define NPATCH 225
#define NTOK 226
#define NSB 128      // 2*B (both streams batched)
#define NROWS (NSB*NTOK)   // 28928

#define VP 232       // attention Vt LDS pitch (bf16 units); 232=8*29 keeps rows 16B-aligned,
                     // dword row-stride 116 ≡ 20 (mod 32) -> ~2-way banks
#define PBP 40       // P chunk-buffer pitch (bf16): 80B rows -> b64/b128 16B-aligned,
                     // dword stride 20 -> 5c mod 8 bijective -> conflict-free

typedef __attribute__((ext_vector_type(8))) short bfrag8;
typedef __attribute__((ext_vector_type(4))) float ffrag4;

// RNE bf16: bit-exact vs __float2bfloat16 for finite inputs, 3 VALU ops.
__device__ __forceinline__ unsigned short f2b(float f) {
  uint32_t u; __builtin_memcpy(&u, &f, 4);
  u += 0x7fff + ((u >> 16) & 1);
  return (unsigned short)(u >> 16);
}

// pack 2 f32 -> 2 bf16 in one u32 (lo = first arg), RNE — single VALU op
__device__ __forceinline__ unsigned pk2(float lo, float hi) {
  unsigned r;
  asm("v_cvt_pk_bf16_f32 %0, %1, %2" : "=v"(r) : "v"(lo), "v"(hi));
  return r;
}

// ---- fusion-matrix diagonal: sdfm[b][d] = sqrt(sigmoid(x @ fmg_w[:,65d])) ----
__global__ void k_dfm(const float* __restrict__ hsi, const float* __restrict__ lidar,
                      const float* __restrict__ fmg_w, float* __restrict__ sdfm) {
  __shared__ float xc[128];
  int b = blockIdx.x, t = threadIdx.x;
  const float* src = (t < 64) ? hsi : lidar;
  int d = t & 63;
  const float* p = src + ((size_t)b * 64 + d) * NPATCH;
  float s = 0.f;
  for (int i = 0; i < NPATCH; ++i) s += p[i];
  xc[t] = s * (1.0f / 225.0f);
  __syncthreads();
  if (t < 64) {
    float acc = 0.f;
    const float* w = fmg_w + t * 65;       // column 65*t of [128,4096]
    for (int c = 0; c < 128; ++c) acc += xc[c] * w[c * 4096];
    float sg = 1.0f / (1.0f + expf(-acc));
    sdfm[b * 64 + t] = sqrtf(sg);
  }
}

// ---- build X[2B,226,64] (+ pos) and Xn = LN1_0(X); one wave per row ----
__global__ void k_build(const float* __restrict__ hsi,
                        const float* __restrict__ cls_h, const float* __restrict__ cls_l,
                        const float* __restrict__ pos_h, const float* __restrict__ pos_l,
                        const float* __restrict__ g, const float* __restrict__ bb,
                        float* __restrict__ X, uint16_t* __restrict__ Xn) {
  int r = blockIdx.x;                 // sb*226 + n
  int sb = r / NTOK, n = r - sb * NTOK;
  int s = sb >> 6, b = sb & 63;
  int d = threadIdx.x;                // 64 threads = 1 wave
  float v;
  if (n == 0) v = s ? cls_l[d] : cls_h[d];
  else        v = hsi[((size_t)b * 64 + d) * NPATCH + (n - 1)];
  v += (s ? pos_l : pos_h)[n * ND + d];
  X[(size_t)r * ND + d] = v;
  float sm = v, sq = v * v;
  #pragma unroll
  for (int o = 32; o; o >>= 1) { sm += __shfl_xor(sm, o); sq += __shfl_xor(sq, o); }
  float m = sm * (1.f / 64.f);
  float rs = rsqrtf(sq * (1.f / 64.f) - m * m + 1e-5f);
  Xn[(size_t)r * ND + d] = f2b((v - m) * rs * g[d] + bb[d]);
}

// ---- weight convert+transpose to bf16 [col][k] layouts, all layers ----
__global__ __launch_bounds__(256) void k_wconv(
    const float* __restrict__ qkv_w, const float* __restrict__ out_w,
    const float* __restrict__ ff_w1, const float* __restrict__ ff_w2,
    uint16_t* __restrict__ Wqv, uint16_t* __restrict__ Wo,
    uint16_t* __restrict__ W1, uint16_t* __restrict__ W2) {
  int i = blockIdx.x * 256 + threadIdx.x;   // grid covers 524288
  if (i < 262144) {
    int ly = i >> 16, rem = i & 65535, n = rem >> 6, k = rem & 63;
    int col = n + ((n >> 9) << 9);          // n<512 ? q col n : v col n+512
    Wqv[i] = f2b(qkv_w[((size_t)ly * 64 + k) * 1536 + col]);
  } else if (i < 393216) {
    int j = i - 262144;
    int ly = j >> 15, rem = j & 32767, n = rem >> 9, k = rem & 511;
    Wo[j] = f2b(out_w[((size_t)ly * 512 + k) * 64 + n]);
  } else if (i < 458752) {
    int j = i - 393216;
    int ly = j >> 14, rem = j & 16383, n = rem >> 6, k = rem & 63;
    W1[j] = f2b(ff_w1[((size_t)ly * 64 + k) * 256 + n]);
  } else {
    int j = i - 458752;
    int ly = j >> 14, rem = j & 16383, n = rem >> 8, k = rem & 255;
    W2[j] = f2b(ff_w2[((size_t)ly * 256 + k) * 64 + n]);
  }
}

// ---- fused QV-projection + MFMA attention, swapped-operand QK^T ----
// QK^T computed as mfma(K_jt, Q_it): S[i][j] with i = lane&15 (lane-local row).
// Softmax per-lane (2+2 shfl_xor cross-quad, vs 32 in the non-swapped version).
// P -> A-frag transpose via a small per-wave LDS chunk buffer (pb), written as
// packed b64 LAZILY inside the PV loop so the post-max live set is just {s, oa}
// and acc[15] stays in AGPRs (R2's in-register permlane transpose cost 124 VGPR
// and serialized ds_bpermute chains -> latency-bound at 19% occupancy).
// LDS = 30720 (qs) + 29760 (vt) + 10240 (pb) = 70720 B -> 2 blocks/CU.
__global__ __launch_bounds__(512) void k_fattn(const uint16_t* __restrict__ Xn,
    const uint16_t* __restrict__ Wqv,   // [1024][64] this layer
    const float* __restrict__ sdfm, uint16_t* __restrict__ Og) {
  __shared__ __align__(16) uint16_t qs[240 * 64];
  __shared__ __align__(16) uint16_t vt[64 * VP + 32];
  __shared__ __align__(16) uint16_t pb[8][16 * PBP];
  int bh = blockIdx.x;
  int sb = bh >> 3, h = bh & 7;
  int t = threadIdx.x, w = t >> 6, l = t & 63;
  int quad = l >> 4, c = l & 15;
  const uint16_t* Xb = Xn + (size_t)sb * NTOK * ND;

  // zero the tail pad: chunk-7 PV B-reads run past row 63 into this region;
  // values multiply P==0 so they only need to be finite.
  if (t < 32) vt[64 * VP + t] = 0;

  float sf[4];
  #pragma unroll
  for (int dt = 0; dt < 4; ++dt)
    sf[dt] = sdfm[(sb & 63) * 64 + dt * 16 + c] * 0.35355339059327373f;  // sqrt(1/8)

  // phase 1: Q,V projection for this head (8-way wave split)
  for (int it = w; it < 15; it += 8) {
    int i0 = it * 16;
    int ri = i0 + c; if (ri > 225) ri = 225;
    bfrag8 a0 = *(const bfrag8*)(Xb + (size_t)ri * 64 + quad * 8);
    bfrag8 a1 = *(const bfrag8*)(Xb + (size_t)ri * 64 + 32 + quad * 8);
    #pragma unroll
    for (int dt = 0; dt < 4; ++dt) {
      int nq = h * 64 + dt * 16 + c;
      bfrag8 bq0 = *(const bfrag8*)(Wqv + (size_t)nq * 64 + quad * 8);
      bfrag8 bq1 = *(const bfrag8*)(Wqv + (size_t)nq * 64 + 32 + quad * 8);
      ffrag4 zq = {0.f, 0.f, 0.f, 0.f};
      zq = __builtin_amdgcn_mfma_f32_16x16x32_bf16(a0, bq0, zq, 0, 0, 0);
      zq = __builtin_amdgcn_mfma_f32_16x16x32_bf16(a1, bq1, zq, 0, 0, 0);
      bfrag8 bv0 = *(const bfrag8*)(Wqv + (size_t)(512 + nq) * 64 + quad * 8);
      bfrag8 bv1 = *(const bfrag8*)(Wqv + (size_t)(512 + nq) * 64 + 32 + quad * 8);
      ffrag4 zv = {0.f, 0.f, 0.f, 0.f};
      zv = __builtin_amdgcn_mfma_f32_16x16x32_bf16(a0, bv0, zv, 0, 0, 0);
      zv = __builtin_amdgcn_mfma_f32_16x16x32_bf16(a1, bv1, zv, 0, 0, 0);
      int d = dt * 16 + c;
      #pragma unroll
      for (int r = 0; r < 4; ++r) {
        int i = i0 + quad * 4 + r;
        qs[i * 64 + ((((d >> 3) ^ (i & 7))) << 3) + (d & 7)] = f2b(zq[r] * sf[dt]);
      }
      // packed V store: 4 consecutive i -> one b64 write (8B aligned: VP*2 % 8 == 0)
      int iv = i0 + quad * 4;
      if (iv + 3 < VP) {   // skip it=14,quad>=2 (would corrupt next d-row)
        unsigned lo = pk2(zv[0], zv[1]);
        unsigned hi = pk2(zv[2], zv[3]);
        *(unsigned long long*)(vt + (size_t)d * VP + iv) =
            ((unsigned long long)hi << 32) | lo;
      }
    }
  }
  __syncthreads();

  uint16_t* pw = &pb[w][0];
  for (int it = w; it < 15; it += 8) {
    int i0 = it * 16;
    // B-frag = this i-tile's rows (i becomes the MFMA column -> lane-local)
    int rb = i0 + c, sk = rb & 7;
    bfrag8 b0 = *(const bfrag8*)(qs + rb * 64 + ((quad ^ sk) << 3));
    bfrag8 b1 = *(const bfrag8*)(qs + rb * 64 + (((quad + 4) ^ sk) << 3));
    ffrag4 acc[15];
    #pragma unroll
    for (int jt = 0; jt < 15; ++jt) {
      int ra = jt * 16 + c, sa = ra & 7;
      bfrag8 a0 = *(const bfrag8*)(qs + ra * 64 + ((quad ^ sa) << 3));
      bfrag8 a1 = *(const bfrag8*)(qs + ra * 64 + (((quad + 4) ^ sa) << 3));
      ffrag4 z = {0.f, 0.f, 0.f, 0.f};
      z = __builtin_amdgcn_mfma_f32_16x16x32_bf16(a0, b0, z, 0, 0, 0);
      z = __builtin_amdgcn_mfma_f32_16x16x32_bf16(a1, b1, z, 0, 0, 0);
      acc[jt] = z;   // acc[jt][r] = S[i0+c][jt*16 + quad*4 + r]
    }
    // mask invalid j (tile 14: j = 224 + quad*4 + r >= 226)
    #pragma unroll
    for (int r = 0; r < 4; ++r)
      if (quad * 4 + r >= 2) acc[14][r] = -1e30f;
    // max per lane: i = i0 + c fixed; reduce over (jt, r) in-reg, quads via shfl
    float m = -1e30f;
    #pragma unroll
    for (int jt = 0; jt < 15; ++jt)
      #pragma unroll
      for (int r = 0; r < 4; ++r) m = fmaxf(m, acc[jt][r]);
    m = fmaxf(m, __shfl_xor(m, 16));
    m = fmaxf(m, __shfl_xor(m, 32));

    // PV with lazy exp/pack/store: per 32-j chunk, exp the two source tiles,
    // pack to bf16, b64-store into the per-wave chunk buffer (pw row = i-local
    // = c, col = j-local), then b128-read the A-frag. Same-wave RAW: compiler
    // inserts lgkmcnt; no barrier (pb is wave-private).
    float s = 0.f;
    ffrag4 oa[4];
    #pragma unroll
    for (int dt = 0; dt < 4; ++dt) oa[dt] = (ffrag4){0.f, 0.f, 0.f, 0.f};
    #pragma unroll
    for (int jj = 0; jj < 8; ++jj) {
      #pragma unroll
      for (int par = 0; par < 2; ++par) {
        int jt = 2 * jj + par;
        unsigned long long pkv = 0ull;
        if (jt < 15) {
          float e0 = __expf(acc[jt][0] - m);
          float e1 = __expf(acc[jt][1] - m);
          float e2 = __expf(acc[jt][2] - m);
          float e3 = __expf(acc[jt][3] - m);
          s += (e0 + e1) + (e2 + e3);
          pkv = ((unsigned long long)pk2(e2, e3) << 32) | pk2(e0, e1);
        }
        *(unsigned long long*)(pw + c * PBP + par * 16 + quad * 4) = pkv;
      }
      bfrag8 pa = *(const bfrag8*)(pw + c * PBP + quad * 8);
      int j0 = jj * 32;
      #pragma unroll
      for (int dt = 0; dt < 4; ++dt) {
        bfrag8 vb = *(const bfrag8*)(vt + (dt * 16 + c) * VP + j0 + quad * 8);
        oa[dt] = __builtin_amdgcn_mfma_f32_16x16x32_bf16(pa, vb, oa[dt], 0, 0, 0);
      }
    }
    s += __shfl_xor(s, 16);
    s += __shfl_xor(s, 32);
    float rinv = 1.f / s;

    // broadcast 1/l to the C-layout rows (i = i0 + quad*4 + r)
    float rr[4];
    #pragma unroll
    for (int r = 0; r < 4; ++r) rr[r] = __shfl(rinv, quad * 4 + r);
    #pragma unroll
    for (int dt = 0; dt < 4; ++dt) {
      #pragma unroll
      for (int r = 0; r < 4; ++r) {
        int i = i0 + quad * 4 + r;
        if (i < NTOK)
          Og[((size_t)sb * NTOK + i) * NIN + h * DH + dt * 16 + c] =
              f2b(oa[dt][r] * rr[r]);
      }
    }
  }
}

// ---- merged proj+FF, one wave per 16-row tile (unchanged) ----
__global__ __launch_bounds__(64) void k_pf(const uint16_t* __restrict__ Og,
    const uint16_t* __restrict__ Wot,   // [64][512] bf16
    const float* __restrict__ bo, float* __restrict__ X,
    const float* __restrict__ g2, const float* __restrict__ bb2,
    const uint16_t* __restrict__ W1t,   // [256][64] bf16
    const float* __restrict__ b1,
    const uint16_t* __restrict__ W2t,   // [64][256] bf16
    const float* __restrict__ b2,
    const float* __restrict__ gn, const float* __restrict__ bbn,
    uint16_t* __restrict__ XnOut) {
  __shared__ __align__(16) uint16_t xa2[16 * 72];    // 2304 B
  __shared__ __align__(16) uint16_t ha[16 * 264];    // 8448 B
  int t = threadIdx.x;                 // 64 = 1 wave
  int quad = t >> 4, c = t & 15;
  int r0 = blockIdx.x * 16;

  // ---- proj part ----
  const uint16_t* orow = Og + (size_t)(r0 + c) * 512 + quad * 8;
  bfrag8 a[16];
  #pragma unroll
  for (int kc = 0; kc < 16; ++kc) a[kc] = *(const bfrag8*)(orow + kc * 32);
  ffrag4 acc[4];
  #pragma unroll
  for (int jt = 0; jt < 4; ++jt) acc[jt] = (ffrag4){0.f, 0.f, 0.f, 0.f};
  #pragma unroll
  for (int kc = 0; kc < 16; ++kc) {
    #pragma unroll
    for (int jt = 0; jt < 4; ++jt) {
      bfrag8 b = *(const bfrag8*)(Wot + (size_t)(jt * 16 + c) * 512 + kc * 32 + quad * 8);
      acc[jt] = __builtin_amdgcn_mfma_f32_16x16x32_bf16(a[kc], b, acc[jt], 0, 0, 0);
    }
  }
  float xv[4][4];
  #pragma unroll
  for (int jt = 0; jt < 4; ++jt) {
    float bv = bo[jt * 16 + c];
    #pragma unroll
    for (int r = 0; r < 4; ++r) {
      int il = quad * 4 + r;
      size_t idx = (size_t)(r0 + il) * 64 + jt * 16 + c;
      float v = X[idx] + acc[jt][r] + bv;
      X[idx] = v;
      xv[jt][r] = v;
    }
  }
  // LN2 -> xa2 (single wave; program-order LDS, no barrier)
  #pragma unroll
  for (int r = 0; r < 4; ++r) {
    float s = xv[0][r] + xv[1][r] + xv[2][r] + xv[3][r];
    float q = xv[0][r]*xv[0][r] + xv[1][r]*xv[1][r] + xv[2][r]*xv[2][r] + xv[3][r]*xv[3][r];
    #pragma unroll
    for (int o = 8; o; o >>= 1) { s += __shfl_xor(s, o); q += __shfl_xor(q, o); }
    float m = s * (1.f / 64.f);
    float rs = rsqrtf(q * (1.f / 64.f) - m * m + 1e-5f);
    int il = quad * 4 + r;
    #pragma unroll
    for (int jt = 0; jt < 4; ++jt) {
      int n = jt * 16 + c;
      xa2[il * 72 + n] = f2b((xv[jt][r] - m) * rs * g2[n] + bb2[n]);
    }
  }
  // ---- FF part ----
  const uint16_t* xrow = xa2 + c * 72;
  bfrag8 a0 = *(const bfrag8*)(xrow + quad * 8);
  bfrag8 a1 = *(const bfrag8*)(xrow + 32 + quad * 8);
  ffrag4 acc1[16];
  #pragma unroll
  for (int jt = 0; jt < 16; ++jt) {
    bfrag8 b0  = *(const bfrag8*)(W1t + (size_t)(jt * 16 + c) * 64 + quad * 8);
    bfrag8 b1f = *(const bfrag8*)(W1t + (size_t)(jt * 16 + c) * 64 + 32 + quad * 8);
    ffrag4 z = {0.f, 0.f, 0.f, 0.f};
    z = __builtin_amdgcn_mfma_f32_16x16x32_bf16(a0, b0, z, 0, 0, 0);
    z = __builtin_amdgcn_mfma_f32_16x16x32_bf16(a1, b1f, z, 0, 0, 0);
    acc1[jt] = z;
  }
  #pragma unroll
  for (int jt = 0; jt < 16; ++jt) {
    float bv = b1[jt * 16 + c];
    #pragma unroll
    for (int r = 0; r < 4; ++r) {
      float z = acc1[jt][r] + bv;
      float hg = 0.5f * z * (1.f + erff(z * 0.7071067811865476f));
      ha[(quad * 4 + r) * 264 + jt * 16 + c] = f2b(hg);
    }
  }
  ffrag4 o2[4];
  #pragma unroll
  for (int jt = 0; jt < 4; ++jt) o2[jt] = (ffrag4){0.f, 0.f, 0.f, 0.f};
  #pragma unroll
  for (int kc = 0; kc < 8; ++kc) {
    bfrag8 pa = *(const bfrag8*)(ha + c * 264 + kc * 32 + quad * 8);
    #pragma unroll
    for (int jt = 0; jt < 4; ++jt) {
      bfrag8 vb = *(const bfrag8*)(W2t + (size_t)(jt * 16 + c) * 256 + kc * 32 + quad * 8);
      o2[jt] = __builtin_amdgcn_mfma_f32_16x16x32_bf16(pa, vb, o2[jt], 0, 0, 0);
    }
  }
  float yv[4][4];
  #pragma unroll
  for (int jt = 0; jt < 4; ++jt) {
    float bv = b2[jt * 16 + c];
    #pragma unroll
    for (int r = 0; r < 4; ++r) {
      int il = quad * 4 + r;
      size_t idx = (size_t)(r0 + il) * 64 + jt * 16 + c;
      float v = X[idx] + o2[jt][r] + bv;
      X[idx] = v;
      yv[jt][r] = v;
    }
  }
  #pragma unroll
  for (int r = 0; r < 4; ++r) {
    float s = yv[0][r] + yv[1][r] + yv[2][r] + yv[3][r];
    float q = yv[0][r]*yv[0][r] + yv[1][r]*yv[1][r] + yv[2][r]*yv[2][r] + yv[3][r]*yv[3][r];
    #pragma unroll
    for (int o = 8; o; o >>= 1) { s += __shfl_xor(s, o); q += __shfl_xor(q, o); }
    float m = s * (1.f / 64.f);
    float rs = rsqrtf(q * (1.f / 64.f) - m * m + 1e-5f);
    int il = quad * 4 + r;
    #pragma unroll
    for (int jt = 0; jt < 4; ++jt) {
      int n = jt * 16 + c;
      XnOut[(size_t)(r0 + il) * 64 + n] = f2b((yv[jt][r] - m) * rs * gn[n] + bbn[n]);
    }
  }
}

// ---- swap cls tokens between streams; refresh Xn (LN1 layer0) for those rows ----
__global__ void k_xchg(float* __restrict__ X, uint16_t* __restrict__ Xn,
                       const float* __restrict__ g, const float* __restrict__ bb) {
  int b = blockIdx.x, d = threadIdx.x;   // 64 blocks x 64 threads (1 wave)
  size_t i0 = (size_t)(b * NTOK) * ND + d;
  size_t i1 = (size_t)((64 + b) * NTOK) * ND + d;
  float a = X[i0], cc = X[i1];
  X[i0] = cc; X[i1] = a;
  float s0 = cc, q0 = cc * cc, s1 = a, q1 = a * a;
  #pragma unroll
  for (int o = 32; o; o >>= 1) {
    s0 += __shfl_xor(s0, o); q0 += __shfl_xor(q0, o);
    s1 += __shfl_xor(s1, o); q1 += __shfl_xor(q1, o);
  }
  float m0 = s0 * (1.f / 64.f), rs0 = rsqrtf(q0 * (1.f / 64.f) - m0 * m0 + 1e-5f);
  float m1 = s1 * (1.f / 64.f), rs1 = rsqrtf(q1 * (1.f / 64.f) - m1 * m1 + 1e-5f);
  Xn[i0] = f2b((cc - m0) * rs0 * g[d] + bb[d]);
  Xn[i1] = f2b((a - m1) * rs1 * g[d] + bb[d]);
}

// ---- final: out = h_cls + l_cls ----
__global__ void k_out(const float* __restrict__ X, float* __restrict__ out) {
  int i = blockIdx.x * 64 + threadIdx.x;
  int b = i >> 6, d = i & 63;
  out[i] = X[(size_t)b * NTOK * ND + d] + X[(size_t)(64 + b) * NTOK * ND + d];
}

extern "C" void kernel_launch(void* const* d_in, const int* in_sizes, int n_in,
                              void* d_out, int out_size, void* d_ws, size_t ws_size,
                              hipStream_t stream) {
  const float* hsi   = (const float*)d_in[0];
  const float* lidar = (const float*)d_in[1];
  const float* cls_h = (const float*)d_in[2];
  const float* cls_l = (const float*)d_in[3];
  const float* pos_h = (const float*)d_in[4];
  const float* pos_l = (const float*)d_in[5];
  const float* fmg_w = (const float*)d_in[6];
  const float* ln1_g = (const float*)d_in[7];
  const float* ln1_b = (const float*)d_in[8];
  const float* qkv_w = (const float*)d_in[9];
  const float* out_w = (const float*)d_in[10];
  const float* out_b = (const float*)d_in[11];
  const float* ln2_g = (const float*)d_in[12];
  const float* ln2_b = (const float*)d_in[13];
  const float* ff_w1 = (const float*)d_in[14];
  const float* ff_b1 = (const float*)d_in[15];
  const float* ff_w2 = (const float*)d_in[16];
  const float* ff_b2 = (const float*)d_in[17];

  char* ws = (char*)d_ws;
  float*    X    = (float*)ws;                       // 7,405,568 B
  float*    sdfm = (float*)(ws + 7405568);           // 16,384 B
  uint16_t* Xn   = (uint16_t*)(ws + 7421952);        // 3,702,784 B
  uint16_t* Og   = (uint16_t*)(ws + 11124736);       // 29,622,272 B
  uint16_t* Wqv  = (uint16_t*)(ws + 40747008);       // 524,288 B
  uint16_t* Wo   = (uint16_t*)(ws + 41271296);       // 262,144 B
  uint16_t* W1   = (uint16_t*)(ws + 41533440);       // 131,072 B
  uint16_t* W2   = (uint16_t*)(ws + 41664512);       // 131,072 B -> end 41,795,584

  k_wconv<<<2048, 256, 0, stream>>>(qkv_w, out_w, ff_w1, ff_w2, Wqv, Wo, W1, W2);
  k_dfm<<<NB, 128, 0, stream>>>(hsi, lidar, fmg_w, sdfm);
  k_build<<<NROWS, 64, 0, stream>>>(hsi, cls_h, cls_l, pos_h, pos_l,
                                    ln1_g, ln1_b, X, Xn);
  for (int pass = 0; pass < 2; ++pass) {
    for (int ly = 0; ly < NDEPTH; ++ly) {
      int nx = (ly + 1) & 3;   // next layer's LN1 params (harmless on final layer)
      k_fattn<<<NSB * NH, 512, 0, stream>>>(Xn, Wqv + (size_t)ly * 65536, sdfm, Og);
      k_pf<<<NROWS / 16, 64, 0, stream>>>(Og, Wo + (size_t)ly * 32768, out_b + ly * ND,
                                          X, ln2_g + ly * ND, ln2_b + ly * ND,
                                          W1 + (size_t)ly * 16384, ff_b1 + ly * NMLP,
                                          W2 + (size_t)ly * 16384, ff_b2 + ly * ND,
                                          ln1_g + nx * ND, ln1_b + nx * ND, Xn);
    }
    if (pass == 0) k_xchg<<<64, 64, 0, stream>>>(X, Xn, ln1_g, ln1_b);
  }
  k_out<<<64, 64, 0, stream>>>(X, (float*)d_out);
}

// Round 7
// 805.745 us; speedup vs baseline: 1.7063x; 1.1035x over previous
//
#include <hip/hip_runtime.h>
#include <hip/hip_bf16.h>
#include <cstdint>

#define NB 64        // batch
#define ND 64        // DIM
#define NH 8         // heads
#define DH 64        // dim_head
#define NIN 512      // inner
#define NMLP 256
#define NDEPTH 4
#define NPATCH 225
#define NTOK 226
#define NSB 128      // 2*B (both streams batched)
#define NROWS (NSB*NTOK)   // 28928

#define VP 240       // attention Vt LDS pitch (bf16 units) — R0-validated
#define PBP 40       // P buffer pitch (bf16). 80B rows: b128 reads 16B-ALIGNED
                     // (PBP=36's 72B rows were only 8B-aligned -> compiler-merged
                     // ds_read_b128 was misaligned for odd c = R5/R6 corruption).
                     // Store banks: dword = 80q + 20r + c/2 -> 4-way (vs 8-way @32).
                     // Read-at-pitch-40 pattern is R3-hardware-validated.

typedef __attribute__((ext_vector_type(8))) short bfrag8;
typedef __attribute__((ext_vector_type(4))) float ffrag4;

// RNE bf16: bit-exact vs __float2bfloat16 for finite inputs, 3 VALU ops.
__device__ __forceinline__ unsigned short f2b(float f) {
  uint32_t u; __builtin_memcpy(&u, &f, 4);
  u += 0x7fff + ((u >> 16) & 1);
  return (unsigned short)(u >> 16);
}

// ---- fusion-matrix diagonal: sdfm[b][d] = sqrt(sigmoid(x @ fmg_w[:,65d])) ----
__global__ void k_dfm(const float* __restrict__ hsi, const float* __restrict__ lidar,
                      const float* __restrict__ fmg_w, float* __restrict__ sdfm) {
  __shared__ float xc[128];
  int b = blockIdx.x, t = threadIdx.x;
  const float* src = (t < 64) ? hsi : lidar;
  int d = t & 63;
  const float* p = src + ((size_t)b * 64 + d) * NPATCH;
  float s = 0.f;
  for (int i = 0; i < NPATCH; ++i) s += p[i];
  xc[t] = s * (1.0f / 225.0f);
  __syncthreads();
  if (t < 64) {
    float acc = 0.f;
    const float* w = fmg_w + t * 65;       // column 65*t of [128,4096]
    for (int c = 0; c < 128; ++c) acc += xc[c] * w[c * 4096];
    float sg = 1.0f / (1.0f + expf(-acc));
    sdfm[b * 64 + t] = sqrtf(sg);
  }
}

// ---- build X[2B,226,64] (+ pos) and Xn = LN1_0(X); one wave per row ----
__global__ void k_build(const float* __restrict__ hsi,
                        const float* __restrict__ cls_h, const float* __restrict__ cls_l,
                        const float* __restrict__ pos_h, const float* __restrict__ pos_l,
                        const float* __restrict__ g, const float* __restrict__ bb,
                        float* __restrict__ X, uint16_t* __restrict__ Xn) {
  int r = blockIdx.x;                 // sb*226 + n
  int sb = r / NTOK, n = r - sb * NTOK;
  int s = sb >> 6, b = sb & 63;
  int d = threadIdx.x;                // 64 threads = 1 wave
  float v;
  if (n == 0) v = s ? cls_l[d] : cls_h[d];
  else        v = hsi[((size_t)b * 64 + d) * NPATCH + (n - 1)];
  v += (s ? pos_l : pos_h)[n * ND + d];
  X[(size_t)r * ND + d] = v;
  float sm = v, sq = v * v;
  #pragma unroll
  for (int o = 32; o; o >>= 1) { sm += __shfl_xor(sm, o); sq += __shfl_xor(sq, o); }
  float m = sm * (1.f / 64.f);
  float rs = rsqrtf(sq * (1.f / 64.f) - m * m + 1e-5f);
  Xn[(size_t)r * ND + d] = f2b((v - m) * rs * g[d] + bb[d]);
}

// ---- weight convert+transpose to bf16 [col][k] layouts, all layers ----
__global__ __launch_bounds__(256) void k_wconv(
    const float* __restrict__ qkv_w, const float* __restrict__ out_w,
    const float* __restrict__ ff_w1, const float* __restrict__ ff_w2,
    uint16_t* __restrict__ Wqv, uint16_t* __restrict__ Wo,
    uint16_t* __restrict__ W1, uint16_t* __restrict__ W2) {
  int i = blockIdx.x * 256 + threadIdx.x;   // grid covers 524288
  if (i < 262144) {
    int ly = i >> 16, rem = i & 65535, n = rem >> 6, k = rem & 63;
    int col = n + ((n >> 9) << 9);          // n<512 ? q col n : v col n+512
    Wqv[i] = f2b(qkv_w[((size_t)ly * 64 + k) * 1536 + col]);
  } else if (i < 393216) {
    int j = i - 262144;
    int ly = j >> 15, rem = j & 32767, n = rem >> 9, k = rem & 511;
    Wo[j] = f2b(out_w[((size_t)ly * 512 + k) * 64 + n]);
  } else if (i < 458752) {
    int j = i - 393216;
    int ly = j >> 14, rem = j & 16383, n = rem >> 6, k = rem & 63;
    W1[j] = f2b(ff_w1[((size_t)ly * 64 + k) * 256 + n]);
  } else {
    int j = i - 458752;
    int ly = j >> 14, rem = j & 16383, n = rem >> 8, k = rem & 255;
    W2[j] = f2b(ff_w2[((size_t)ly * 256 + k) * 64 + n]);
  }
}

// ---- fused QV-projection + MFMA attention: EXACT R0 structure (51.9us, 56
// VGPR, passed twice). ONE change: pb pitch 32 -> 40 (16B-aligned rows, 4-way
// stores instead of 8-way). All values stored/read identical to R0.
// LDS = 30720 (qs) + 30720 (vt) + 10240 (pb) = 71680 B -> 2 blocks/CU.
__global__ __launch_bounds__(512) void k_fattn(const uint16_t* __restrict__ Xn,
    const uint16_t* __restrict__ Wqv,   // [1024][64] this layer
    const float* __restrict__ sdfm, uint16_t* __restrict__ Og) {
  __shared__ __align__(16) uint16_t qs[240 * 64];
  __shared__ __align__(16) uint16_t vt[64 * VP];
  __shared__ __align__(16) uint16_t pb[8][16 * PBP];
  int bh = blockIdx.x;
  int sb = bh >> 3, h = bh & 7;
  int t = threadIdx.x, w = t >> 6, l = t & 63;
  int quad = l >> 4, c = l & 15;
  const uint16_t* Xb = Xn + (size_t)sb * NTOK * ND;

  float sf[4];
  #pragma unroll
  for (int dt = 0; dt < 4; ++dt)
    sf[dt] = sdfm[(sb & 63) * 64 + dt * 16 + c] * 0.35355339059327373f;  // sqrt(1/8)

  // phase 1: Q,V projection for this head (8-way wave split)
  for (int it = w; it < 15; it += 8) {
    int i0 = it * 16;
    int ri = i0 + c; if (ri > 225) ri = 225;
    bfrag8 a0 = *(const bfrag8*)(Xb + (size_t)ri * 64 + quad * 8);
    bfrag8 a1 = *(const bfrag8*)(Xb + (size_t)ri * 64 + 32 + quad * 8);
    #pragma unroll
    for (int dt = 0; dt < 4; ++dt) {
      int nq = h * 64 + dt * 16 + c;
      bfrag8 bq0 = *(const bfrag8*)(Wqv + (size_t)nq * 64 + quad * 8);
      bfrag8 bq1 = *(const bfrag8*)(Wqv + (size_t)nq * 64 + 32 + quad * 8);
      ffrag4 zq = {0.f, 0.f, 0.f, 0.f};
      zq = __builtin_amdgcn_mfma_f32_16x16x32_bf16(a0, bq0, zq, 0, 0, 0);
      zq = __builtin_amdgcn_mfma_f32_16x16x32_bf16(a1, bq1, zq, 0, 0, 0);
      bfrag8 bv0 = *(const bfrag8*)(Wqv + (size_t)(512 + nq) * 64 + quad * 8);
      bfrag8 bv1 = *(const bfrag8*)(Wqv + (size_t)(512 + nq) * 64 + 32 + quad * 8);
      ffrag4 zv = {0.f, 0.f, 0.f, 0.f};
      zv = __builtin_amdgcn_mfma_f32_16x16x32_bf16(a0, bv0, zv, 0, 0, 0);
      zv = __builtin_amdgcn_mfma_f32_16x16x32_bf16(a1, bv1, zv, 0, 0, 0);
      int d = dt * 16 + c;
      #pragma unroll
      for (int r = 0; r < 4; ++r) {
        int i = i0 + quad * 4 + r;
        qs[i * 64 + ((((d >> 3) ^ (i & 7))) << 3) + (d & 7)] = f2b(zq[r] * sf[dt]);
        vt[d * VP + i] = f2b(zv[r]);
      }
    }
  }
  __syncthreads();

  uint16_t* pw = &pb[w][0];
  for (int it = w; it < 15; it += 8) {
    int i0 = it * 16;
    int ra = i0 + c, sa = ra & 7;
    bfrag8 a0 = *(const bfrag8*)(qs + ra * 64 + ((quad ^ sa) << 3));
    bfrag8 a1 = *(const bfrag8*)(qs + ra * 64 + (((quad + 4) ^ sa) << 3));
    ffrag4 acc[15];
    #pragma unroll
    for (int jt = 0; jt < 15; ++jt) {
      int rb = jt * 16 + c, sk = rb & 7;
      bfrag8 b0 = *(const bfrag8*)(qs + rb * 64 + ((quad ^ sk) << 3));
      bfrag8 b1 = *(const bfrag8*)(qs + rb * 64 + (((quad + 4) ^ sk) << 3));
      ffrag4 z = {0.f, 0.f, 0.f, 0.f};
      z = __builtin_amdgcn_mfma_f32_16x16x32_bf16(a0, b0, z, 0, 0, 0);
      z = __builtin_amdgcn_mfma_f32_16x16x32_bf16(a1, b1, z, 0, 0, 0);
      acc[jt] = z;
    }
    // softmax: store raw E = exp(S - m); 1/l applied at O store
    float rinv[4];
    #pragma unroll
    for (int r = 0; r < 4; ++r) {
      float m = -1e30f;
      #pragma unroll
      for (int jt = 0; jt < 15; ++jt) m = fmaxf(m, acc[jt][r]);
      #pragma unroll
      for (int o = 8; o; o >>= 1) m = fmaxf(m, __shfl_xor(m, o));
      float s = 0.f;
      #pragma unroll
      for (int jt = 0; jt < 15; ++jt) {
        float p = __expf(acc[jt][r] - m);
        if (jt == 14 && c >= 2) p = 0.f;   // j = 224+c >= 226 invalid (dup rows)
        acc[jt][r] = p;
        s += p;
      }
      #pragma unroll
      for (int o = 8; o; o >>= 1) s += __shfl_xor(s, o);
      rinv[r] = 1.f / s;
    }
    ffrag4 oa[4];
    #pragma unroll
    for (int dt = 0; dt < 4; ++dt) oa[dt] = (ffrag4){0.f, 0.f, 0.f, 0.f};
    for (int jc = 0; jc < 8; ++jc) {
      if (jc == 7) {
        *(unsigned long long*)(pw + c * PBP + 16 + quad * 4) = 0ull;  // zero E cols 16..31
      }
      #pragma unroll
      for (int r = 0; r < 4; ++r) {
        int row = quad * 4 + r;
        pw[row * PBP + c] = f2b(acc[2 * jc][r]);
        if (jc < 7) pw[row * PBP + 16 + c] = f2b(acc[2 * jc + 1][r]);
      }
      bfrag8 pa = *(const bfrag8*)(pw + c * PBP + quad * 8);  // byte 80c+16q: 16B-aligned
      int j0 = jc * 32;
      #pragma unroll
      for (int dt = 0; dt < 4; ++dt) {
        bfrag8 vb;
        if (jc < 7)
          vb = *(const bfrag8*)(vt + (dt * 16 + c) * VP + j0 + quad * 8);
        else
          vb = *(const bfrag8*)(vt + (dt * 16 + c) * VP + 224 + (quad & 1) * 8);
        oa[dt] = __builtin_amdgcn_mfma_f32_16x16x32_bf16(pa, vb, oa[dt], 0, 0, 0);
      }
    }
    #pragma unroll
    for (int dt = 0; dt < 4; ++dt) {
      #pragma unroll
      for (int r = 0; r < 4; ++r) {
        int i = i0 + quad * 4 + r;
        if (i < NTOK)
          Og[((size_t)sb * NTOK + i) * NIN + h * DH + dt * 16 + c] =
              f2b(oa[dt][r] * rinv[r]);
      }
    }
  }
}

// ---- merged proj+FF, one wave per 16-row tile (unchanged R0) ----
__global__ __launch_bounds__(64) void k_pf(const uint16_t* __restrict__ Og,
    const uint16_t* __restrict__ Wot,   // [64][512] bf16
    const float* __restrict__ bo, float* __restrict__ X,
    const float* __restrict__ g2, const float* __restrict__ bb2,
    const uint16_t* __restrict__ W1t,   // [256][64] bf16
    const float* __restrict__ b1,
    const uint16_t* __restrict__ W2t,   // [64][256] bf16
    const float* __restrict__ b2,
    const float* __restrict__ gn, const float* __restrict__ bbn,
    uint16_t* __restrict__ XnOut) {
  __shared__ __align__(16) uint16_t xa2[16 * 72];    // 2304 B
  __shared__ __align__(16) uint16_t ha[16 * 264];    // 8448 B
  int t = threadIdx.x;                 // 64 = 1 wave
  int quad = t >> 4, c = t & 15;
  int r0 = blockIdx.x * 16;

  // ---- proj part ----
  const uint16_t* orow = Og + (size_t)(r0 + c) * 512 + quad * 8;
  bfrag8 a[16];
  #pragma unroll
  for (int kc = 0; kc < 16; ++kc) a[kc] = *(const bfrag8*)(orow + kc * 32);
  ffrag4 acc[4];
  #pragma unroll
  for (int jt = 0; jt < 4; ++jt) acc[jt] = (ffrag4){0.f, 0.f, 0.f, 0.f};
  #pragma unroll
  for (int kc = 0; kc < 16; ++kc) {
    #pragma unroll
    for (int jt = 0; jt < 4; ++jt) {
      bfrag8 b = *(const bfrag8*)(Wot + (size_t)(jt * 16 + c) * 512 + kc * 32 + quad * 8);
      acc[jt] = __builtin_amdgcn_mfma_f32_16x16x32_bf16(a[kc], b, acc[jt], 0, 0, 0);
    }
  }
  float xv[4][4];
  #pragma unroll
  for (int jt = 0; jt < 4; ++jt) {
    float bv = bo[jt * 16 + c];
    #pragma unroll
    for (int r = 0; r < 4; ++r) {
      int il = quad * 4 + r;
      size_t idx = (size_t)(r0 + il) * 64 + jt * 16 + c;
      float v = X[idx] + acc[jt][r] + bv;
      X[idx] = v;
      xv[jt][r] = v;
    }
  }
  // LN2 -> xa2 (single wave; program-order LDS, no barrier)
  #pragma unroll
  for (int r = 0; r < 4; ++r) {
    float s = xv[0][r] + xv[1][r] + xv[2][r] + xv[3][r];
    float q = xv[0][r]*xv[0][r] + xv[1][r]*xv[1][r] + xv[2][r]*xv[2][r] + xv[3][r]*xv[3][r];
    #pragma unroll
    for (int o = 8; o; o >>= 1) { s += __shfl_xor(s, o); q += __shfl_xor(q, o); }
    float m = s * (1.f / 64.f);
    float rs = rsqrtf(q * (1.f / 64.f) - m * m + 1e-5f);
    int il = quad * 4 + r;
    #pragma unroll
    for (int jt = 0; jt < 4; ++jt) {
      int n = jt * 16 + c;
      xa2[il * 72 + n] = f2b((xv[jt][r] - m) * rs * g2[n] + bb2[n]);
    }
  }
  // ---- FF part ----
  const uint16_t* xrow = xa2 + c * 72;
  bfrag8 a0 = *(const bfrag8*)(xrow + quad * 8);
  bfrag8 a1 = *(const bfrag8*)(xrow + 32 + quad * 8);
  ffrag4 acc1[16];
  #pragma unroll
  for (int jt = 0; jt < 16; ++jt) {
    bfrag8 b0  = *(const bfrag8*)(W1t + (size_t)(jt * 16 + c) * 64 + quad * 8);
    bfrag8 b1f = *(const bfrag8*)(W1t + (size_t)(jt * 16 + c) * 64 + 32 + quad * 8);
    ffrag4 z = {0.f, 0.f, 0.f, 0.f};
    z = __builtin_amdgcn_mfma_f32_16x16x32_bf16(a0, b0, z, 0, 0, 0);
    z = __builtin_amdgcn_mfma_f32_16x16x32_bf16(a1, b1f, z, 0, 0, 0);
    acc1[jt] = z;
  }
  #pragma unroll
  for (int jt = 0; jt < 16; ++jt) {
    float bv = b1[jt * 16 + c];
    #pragma unroll
    for (int r = 0; r < 4; ++r) {
      float z = acc1[jt][r] + bv;
      float hg = 0.5f * z * (1.f + erff(z * 0.7071067811865476f));
      ha[(quad * 4 + r) * 264 + jt * 16 + c] = f2b(hg);
    }
  }
  ffrag4 o2[4];
  #pragma unroll
  for (int jt = 0; jt < 4; ++jt) o2[jt] = (ffrag4){0.f, 0.f, 0.f, 0.f};
  #pragma unroll
  for (int kc = 0; kc < 8; ++kc) {
    bfrag8 pa = *(const bfrag8*)(ha + c * 264 + kc * 32 + quad * 8);
    #pragma unroll
    for (int jt = 0; jt < 4; ++jt) {
      bfrag8 vb = *(const bfrag8*)(W2t + (size_t)(jt * 16 + c) * 256 + kc * 32 + quad * 8);
      o2[jt] = __builtin_amdgcn_mfma_f32_16x16x32_bf16(pa, vb, o2[jt], 0, 0, 0);
    }
  }
  float yv[4][4];
  #pragma unroll
  for (int jt = 0; jt < 4; ++jt) {
    float bv = b2[jt * 16 + c];
    #pragma unroll
    for (int r = 0; r < 4; ++r) {
      int il = quad * 4 + r;
      size_t idx = (size_t)(r0 + il) * 64 + jt * 16 + c;
      float v = X[idx] + o2[jt][r] + bv;
      X[idx] = v;
      yv[jt][r] = v;
    }
  }
  #pragma unroll
  for (int r = 0; r < 4; ++r) {
    float s = yv[0][r] + yv[1][r] + yv[2][r] + yv[3][r];
    float q = yv[0][r]*yv[0][r] + yv[1][r]*yv[1][r] + yv[2][r]*yv[2][r] + yv[3][r]*yv[3][r];
    #pragma unroll
    for (int o = 8; o; o >>= 1) { s += __shfl_xor(s, o); q += __shfl_xor(q, o); }
    float m = s * (1.f / 64.f);
    float rs = rsqrtf(q * (1.f / 64.f) - m * m + 1e-5f);
    int il = quad * 4 + r;
    #pragma unroll
    for (int jt = 0; jt < 4; ++jt) {
      int n = jt * 16 + c;
      XnOut[(size_t)(r0 + il) * 64 + n] = f2b((yv[jt][r] - m) * rs * gn[n] + bbn[n]);
    }
  }
}

// ---- swap cls tokens between streams; refresh Xn (LN1 layer0) for those rows ----
__global__ void k_xchg(float* __restrict__ X, uint16_t* __restrict__ Xn,
                       const float* __restrict__ g, const float* __restrict__ bb) {
  int b = blockIdx.x, d = threadIdx.x;   // 64 blocks x 64 threads (1 wave)
  size_t i0 = (size_t)(b * NTOK) * ND + d;
  size_t i1 = (size_t)((64 + b) * NTOK) * ND + d;
  float a = X[i0], cc = X[i1];
  X[i0] = cc; X[i1] = a;
  float s0 = cc, q0 = cc * cc, s1 = a, q1 = a * a;
  #pragma unroll
  for (int o = 32; o; o >>= 1) {
    s0 += __shfl_xor(s0, o); q0 += __shfl_xor(q0, o);
    s1 += __shfl_xor(s1, o); q1 += __shfl_xor(q1, o);
  }
  float m0 = s0 * (1.f / 64.f), rs0 = rsqrtf(q0 * (1.f / 64.f) - m0 * m0 + 1e-5f);
  float m1 = s1 * (1.f / 64.f), rs1 = rsqrtf(q1 * (1.f / 64.f) - m1 * m1 + 1e-5f);
  Xn[i0] = f2b((cc - m0) * rs0 * g[d] + bb[d]);
  Xn[i1] = f2b((a - m1) * rs1 * g[d] + bb[d]);
}

// ---- final: out = h_cls + l_cls ----
__global__ void k_out(const float* __restrict__ X, float* __restrict__ out) {
  int i = blockIdx.x * 64 + threadIdx.x;
  int b = i >> 6, d = i & 63;
  out[i] = X[(size_t)b * NTOK * ND + d] + X[(size_t)(64 + b) * NTOK * ND + d];
}

extern "C" void kernel_launch(void* const* d_in, const int* in_sizes, int n_in,
                              void* d_out, int out_size, void* d_ws, size_t ws_size,
                              hipStream_t stream) {
  const float* hsi   = (const float*)d_in[0];
  const float* lidar = (const float*)d_in[1];
  const float* cls_h = (const float*)d_in[2];
  const float* cls_l = (const float*)d_in[3];
  const float* pos_h = (const float*)d_in[4];
  const float* pos_l = (const float*)d_in[5];
  const float* fmg_w = (const float*)d_in[6];
  const float* ln1_g = (const float*)d_in[7];
  const float* ln1_b = (const float*)d_in[8];
  const float* qkv_w = (const float*)d_in[9];
  const float* out_w = (const float*)d_in[10];
  const float* out_b = (const float*)d_in[11];
  const float* ln2_g = (const float*)d_in[12];
  const float* ln2_b = (const float*)d_in[13];
  const float* ff_w1 = (const float*)d_in[14];
  const float* ff_b1 = (const float*)d_in[15];
  const float* ff_w2 = (const float*)d_in[16];
  const float* ff_b2 = (const float*)d_in[17];

  char* ws = (char*)d_ws;
  float*    X    = (float*)ws;                       // 7,405,568 B
  float*    sdfm = (float*)(ws + 7405568);           // 16,384 B
  uint16_t* Xn   = (uint16_t*)(ws + 7421952);        // 3,702,784 B
  uint16_t* Og   = (uint16_t*)(ws + 11124736);       // 29,622,272 B
  uint16_t* Wqv  = (uint16_t*)(ws + 40747008);       // 524,288 B
  uint16_t* Wo   = (uint16_t*)(ws + 41271296);       // 262,144 B
  uint16_t* W1   = (uint16_t*)(ws + 41533440);       // 131,072 B
  uint16_t* W2   = (uint16_t*)(ws + 41664512);       // 131,072 B -> end 41,795,584

  k_wconv<<<2048, 256, 0, stream>>>(qkv_w, out_w, ff_w1, ff_w2, Wqv, Wo, W1, W2);
  k_dfm<<<NB, 128, 0, stream>>>(hsi, lidar, fmg_w, sdfm);
  k_build<<<NROWS, 64, 0, stream>>>(hsi, cls_h, cls_l, pos_h, pos_l,
                                    ln1_g, ln1_b, X, Xn);
  for (int pass = 0; pass < 2; ++pass) {
    for (int ly = 0; ly < NDEPTH; ++ly) {
      int nx = (ly + 1) & 3;   // next layer's LN1 params (harmless on final layer)
      k_fattn<<<NSB * NH, 512, 0, stream>>>(Xn, Wqv + (size_t)ly * 65536, sdfm, Og);
      k_pf<<<NROWS / 16, 64, 0, stream>>>(Og, Wo + (size_t)ly * 32768, out_b + ly * ND,
                                          X, ln2_g + ly * ND, ln2_b + ly * ND,
                                          W1 + (size_t)ly * 16384, ff_b1 + ly * NMLP,
                                          W2 + (size_t)ly * 16384, ff_b2 + ly * ND,
                                          ln1_g + nx * ND, ln1_b + nx * ND, Xn);
    }
    if (pass == 0) k_xchg<<<64, 64, 0, stream>>>(X, Xn, ln1_g, ln1_b);
  }
  k_out<<<64, 64, 0, stream>>>(X, (float*)d_out);
}

// Round 9
// 805.396 us; speedup vs baseline: 1.7071x; 1.0004x over previous
//
#include <hip/hip_runtime.h>
#include <hip/hip_bf16.h>
#include <cstdint>

#define NB 64        // batch
#define ND 64        // DIM
#define NH 8         // heads
#define DH 64        // dim_head
#define NIN 512      // inner
#define NMLP 256
#define NDEPTH 4
#define NPATCH 225
#define NTOK 226
#define NSB 128      // 2*B (both streams batched)
#define NROWS (NSB*NTOK)   // 28928

#define VP 240       // attention Vt LDS pitch (bf16 units) — R0/R7-validated
#define PBP 40       // P buffer pitch (bf16): 80B rows keep b128 reads 16B-aligned.
                     // R7-validated: conflicts 3.5M -> 1.29M.

// HARD RULE (R3/R4/R5/R8 forensics): no inline asm consuming fresh MFMA output.
// pk2(v_cvt_pk_bf16_f32) reading MFMA results failed 3 of 4 rounds (scheduling-
// dependent wait-state hazard across the asm boundary). Scalar f2b only.

typedef __attribute__((ext_vector_type(8))) short bfrag8;
typedef __attribute__((ext_vector_type(4))) float ffrag4;

// RNE bf16: bit-exact vs __float2bfloat16 for finite inputs, 3 VALU ops.
__device__ __forceinline__ unsigned short f2b(float f) {
  uint32_t u; __builtin_memcpy(&u, &f, 4);
  u += 0x7fff + ((u >> 16) & 1);
  return (unsigned short)(u >> 16);
}

// ---- fusion-matrix diagonal: sdfm[b][d] = sqrt(sigmoid(x @ fmg_w[:,65d])) ----
__global__ void k_dfm(const float* __restrict__ hsi, const float* __restrict__ lidar,
                      const float* __restrict__ fmg_w, float* __restrict__ sdfm) {
  __shared__ float xc[128];
  int b = blockIdx.x, t = threadIdx.x;
  const float* src = (t < 64) ? hsi : lidar;
  int d = t & 63;
  const float* p = src + ((size_t)b * 64 + d) * NPATCH;
  float s = 0.f;
  for (int i = 0; i < NPATCH; ++i) s += p[i];
  xc[t] = s * (1.0f / 225.0f);
  __syncthreads();
  if (t < 64) {
    float acc = 0.f;
    const float* w = fmg_w + t * 65;       // column 65*t of [128,4096]
    for (int c = 0; c < 128; ++c) acc += xc[c] * w[c * 4096];
    float sg = 1.0f / (1.0f + expf(-acc));
    sdfm[b * 64 + t] = sqrtf(sg);
  }
}

// ---- build X[2B,226,64] (+ pos) and Xn = LN1_0(X); one wave per row ----
__global__ void k_build(const float* __restrict__ hsi,
                        const float* __restrict__ cls_h, const float* __restrict__ cls_l,
                        const float* __restrict__ pos_h, const float* __restrict__ pos_l,
                        const float* __restrict__ g, const float* __restrict__ bb,
                        float* __restrict__ X, uint16_t* __restrict__ Xn) {
  int r = blockIdx.x;                 // sb*226 + n
  int sb = r / NTOK, n = r - sb * NTOK;
  int s = sb >> 6, b = sb & 63;
  int d = threadIdx.x;                // 64 threads = 1 wave
  float v;
  if (n == 0) v = s ? cls_l[d] : cls_h[d];
  else        v = hsi[((size_t)b * 64 + d) * NPATCH + (n - 1)];
  v += (s ? pos_l : pos_h)[n * ND + d];
  X[(size_t)r * ND + d] = v;
  float sm = v, sq = v * v;
  #pragma unroll
  for (int o = 32; o; o >>= 1) { sm += __shfl_xor(sm, o); sq += __shfl_xor(sq, o); }
  float m = sm * (1.f / 64.f);
  float rs = rsqrtf(sq * (1.f / 64.f) - m * m + 1e-5f);
  Xn[(size_t)r * ND + d] = f2b((v - m) * rs * g[d] + bb[d]);
}

// ---- weight convert+transpose to bf16 [col][k] layouts, all layers ----
__global__ __launch_bounds__(256) void k_wconv(
    const float* __restrict__ qkv_w, const float* __restrict__ out_w,
    const float* __restrict__ ff_w1, const float* __restrict__ ff_w2,
    uint16_t* __restrict__ Wqv, uint16_t* __restrict__ Wo,
    uint16_t* __restrict__ W1, uint16_t* __restrict__ W2) {
  int i = blockIdx.x * 256 + threadIdx.x;   // grid covers 524288
  if (i < 262144) {
    int ly = i >> 16, rem = i & 65535, n = rem >> 6, k = rem & 63;
    int col = n + ((n >> 9) << 9);          // n<512 ? q col n : v col n+512
    Wqv[i] = f2b(qkv_w[((size_t)ly * 64 + k) * 1536 + col]);
  } else if (i < 393216) {
    int j = i - 262144;
    int ly = j >> 15, rem = j & 32767, n = rem >> 9, k = rem & 511;
    Wo[j] = f2b(out_w[((size_t)ly * 512 + k) * 64 + n]);
  } else if (i < 458752) {
    int j = i - 393216;
    int ly = j >> 14, rem = j & 16383, n = rem >> 6, k = rem & 63;
    W1[j] = f2b(ff_w1[((size_t)ly * 64 + k) * 256 + n]);
  } else {
    int j = i - 458752;
    int ly = j >> 14, rem = j & 16383, n = rem >> 8, k = rem & 255;
    W2[j] = f2b(ff_w2[((size_t)ly * 256 + k) * 64 + n]);
  }
}

// ---- fused QV-projection + MFMA attention: BYTE-EXACT R7 (passed, 51.3us,
// 56 VGPR, conflicts 1.29M). Scalar f2b vt stores — see HARD RULE above.
// LDS = 30720 (qs) + 30720 (vt) + 10240 (pb) = 71680 B -> 2 blocks/CU.
__global__ __launch_bounds__(512) void k_fattn(const uint16_t* __restrict__ Xn,
    const uint16_t* __restrict__ Wqv,   // [1024][64] this layer
    const float* __restrict__ sdfm, uint16_t* __restrict__ Og) {
  __shared__ __align__(16) uint16_t qs[240 * 64];
  __shared__ __align__(16) uint16_t vt[64 * VP];
  __shared__ __align__(16) uint16_t pb[8][16 * PBP];
  int bh = blockIdx.x;
  int sb = bh >> 3, h = bh & 7;
  int t = threadIdx.x, w = t >> 6, l = t & 63;
  int quad = l >> 4, c = l & 15;
  const uint16_t* Xb = Xn + (size_t)sb * NTOK * ND;

  float sf[4];
  #pragma unroll
  for (int dt = 0; dt < 4; ++dt)
    sf[dt] = sdfm[(sb & 63) * 64 + dt * 16 + c] * 0.35355339059327373f;  // sqrt(1/8)

  // phase 1: Q,V projection for this head (8-way wave split)
  for (int it = w; it < 15; it += 8) {
    int i0 = it * 16;
    int ri = i0 + c; if (ri > 225) ri = 225;
    bfrag8 a0 = *(const bfrag8*)(Xb + (size_t)ri * 64 + quad * 8);
    bfrag8 a1 = *(const bfrag8*)(Xb + (size_t)ri * 64 + 32 + quad * 8);
    #pragma unroll
    for (int dt = 0; dt < 4; ++dt) {
      int nq = h * 64 + dt * 16 + c;
      bfrag8 bq0 = *(const bfrag8*)(Wqv + (size_t)nq * 64 + quad * 8);
      bfrag8 bq1 = *(const bfrag8*)(Wqv + (size_t)nq * 64 + 32 + quad * 8);
      ffrag4 zq = {0.f, 0.f, 0.f, 0.f};
      zq = __builtin_amdgcn_mfma_f32_16x16x32_bf16(a0, bq0, zq, 0, 0, 0);
      zq = __builtin_amdgcn_mfma_f32_16x16x32_bf16(a1, bq1, zq, 0, 0, 0);
      bfrag8 bv0 = *(const bfrag8*)(Wqv + (size_t)(512 + nq) * 64 + quad * 8);
      bfrag8 bv1 = *(const bfrag8*)(Wqv + (size_t)(512 + nq) * 64 + 32 + quad * 8);
      ffrag4 zv = {0.f, 0.f, 0.f, 0.f};
      zv = __builtin_amdgcn_mfma_f32_16x16x32_bf16(a0, bv0, zv, 0, 0, 0);
      zv = __builtin_amdgcn_mfma_f32_16x16x32_bf16(a1, bv1, zv, 0, 0, 0);
      int d = dt * 16 + c;
      #pragma unroll
      for (int r = 0; r < 4; ++r) {
        int i = i0 + quad * 4 + r;
        qs[i * 64 + ((((d >> 3) ^ (i & 7))) << 3) + (d & 7)] = f2b(zq[r] * sf[dt]);
        vt[d * VP + i] = f2b(zv[r]);
      }
    }
  }
  __syncthreads();

  uint16_t* pw = &pb[w][0];
  for (int it = w; it < 15; it += 8) {
    int i0 = it * 16;
    int ra = i0 + c, sa = ra & 7;
    bfrag8 a0 = *(const bfrag8*)(qs + ra * 64 + ((quad ^ sa) << 3));
    bfrag8 a1 = *(const bfrag8*)(qs + ra * 64 + (((quad + 4) ^ sa) << 3));
    ffrag4 acc[15];
    #pragma unroll
    for (int jt = 0; jt < 15; ++jt) {
      int rb = jt * 16 + c, sk = rb & 7;
      bfrag8 b0 = *(const bfrag8*)(qs + rb * 64 + ((quad ^ sk) << 3));
      bfrag8 b1 = *(const bfrag8*)(qs + rb * 64 + (((quad + 4) ^ sk) << 3));
      ffrag4 z = {0.f, 0.f, 0.f, 0.f};
      z = __builtin_amdgcn_mfma_f32_16x16x32_bf16(a0, b0, z, 0, 0, 0);
      z = __builtin_amdgcn_mfma_f32_16x16x32_bf16(a1, b1, z, 0, 0, 0);
      acc[jt] = z;
    }
    // softmax: store raw E = exp(S - m); 1/l applied at O store
    float rinv[4];
    #pragma unroll
    for (int r = 0; r < 4; ++r) {
      float m = -1e30f;
      #pragma unroll
      for (int jt = 0; jt < 15; ++jt) m = fmaxf(m, acc[jt][r]);
      #pragma unroll
      for (int o = 8; o; o >>= 1) m = fmaxf(m, __shfl_xor(m, o));
      float s = 0.f;
      #pragma unroll
      for (int jt = 0; jt < 15; ++jt) {
        float p = __expf(acc[jt][r] - m);
        if (jt == 14 && c >= 2) p = 0.f;   // j = 224+c >= 226 invalid (dup rows)
        acc[jt][r] = p;
        s += p;
      }
      #pragma unroll
      for (int o = 8; o; o >>= 1) s += __shfl_xor(s, o);
      rinv[r] = 1.f / s;
    }
    ffrag4 oa[4];
    #pragma unroll
    for (int dt = 0; dt < 4; ++dt) oa[dt] = (ffrag4){0.f, 0.f, 0.f, 0.f};
    for (int jc = 0; jc < 8; ++jc) {
      if (jc == 7) {
        *(unsigned long long*)(pw + c * PBP + 16 + quad * 4) = 0ull;  // zero E cols 16..31
      }
      #pragma unroll
      for (int r = 0; r < 4; ++r) {
        int row = quad * 4 + r;
        pw[row * PBP + c] = f2b(acc[2 * jc][r]);
        if (jc < 7) pw[row * PBP + 16 + c] = f2b(acc[2 * jc + 1][r]);
      }
      bfrag8 pa = *(const bfrag8*)(pw + c * PBP + quad * 8);  // byte 80c+16q: 16B-aligned
      int j0 = jc * 32;
      #pragma unroll
      for (int dt = 0; dt < 4; ++dt) {
        bfrag8 vb;
        if (jc < 7)
          vb = *(const bfrag8*)(vt + (dt * 16 + c) * VP + j0 + quad * 8);
        else
          vb = *(const bfrag8*)(vt + (dt * 16 + c) * VP + 224 + (quad & 1) * 8);
        oa[dt] = __builtin_amdgcn_mfma_f32_16x16x32_bf16(pa, vb, oa[dt], 0, 0, 0);
      }
    }
    #pragma unroll
    for (int dt = 0; dt < 4; ++dt) {
      #pragma unroll
      for (int r = 0; r < 4; ++r) {
        int i = i0 + quad * 4 + r;
        if (i < NTOK)
          Og[((size_t)sb * NTOK + i) * NIN + h * DH + dt * 16 + c] =
              f2b(oa[dt][r] * rinv[r]);
      }
    }
  }
}

// ---- merged proj+FF: 2 waves per 16-row tile, split along N ----
// R7's k_pf was 1 wave/block: 1808 waves on 8192 slots (~1.8/SIMD) -> pure
// exposed latency (45us vs ~8us roofline). Wave w owns proj/FF2 cols
// 32w..32w+31 (jt = 2w,2w+1) and FF1 h-cols 128w..128w+127 (jt = 8w..8w+7).
// LN row-sums exchanged via lnp[2][16][2]; every cross-wave LDS edge has a
// barrier. Accumulators split by kc parity to halve MFMA dep-chain depth.
__global__ __launch_bounds__(128) void k_pf(const uint16_t* __restrict__ Og,
    const uint16_t* __restrict__ Wot,   // [64][512] bf16
    const float* __restrict__ bo, float* __restrict__ X,
    const float* __restrict__ g2, const float* __restrict__ bb2,
    const uint16_t* __restrict__ W1t,   // [256][64] bf16
    const float* __restrict__ b1,
    const uint16_t* __restrict__ W2t,   // [64][256] bf16
    const float* __restrict__ b2,
    const float* __restrict__ gn, const float* __restrict__ bbn,
    uint16_t* __restrict__ XnOut) {
  __shared__ __align__(16) uint16_t xa2[16 * 72];    // 2304 B
  __shared__ __align__(16) uint16_t ha[16 * 264];    // 8448 B
  __shared__ float lnp[2][16][2];                    // 256 B: [wave][row][s,q]
  int t = threadIdx.x;                 // 128 = 2 waves
  int w = t >> 6, l = t & 63;
  int quad = l >> 4, c = l & 15;
  int r0 = blockIdx.x * 16;

  // ---- proj part: wave w computes jt in {2w, 2w+1} ----
  const uint16_t* orow = Og + (size_t)(r0 + c) * 512 + quad * 8;
  bfrag8 a[16];
  #pragma unroll
  for (int kc = 0; kc < 16; ++kc) a[kc] = *(const bfrag8*)(orow + kc * 32);
  ffrag4 acc[2][2];                    // [jt_local][kc parity] -> chains of 8
  #pragma unroll
  for (int j = 0; j < 2; ++j)
    #pragma unroll
    for (int p = 0; p < 2; ++p) acc[j][p] = (ffrag4){0.f, 0.f, 0.f, 0.f};
  #pragma unroll
  for (int kc = 0; kc < 16; ++kc) {
    #pragma unroll
    for (int j = 0; j < 2; ++j) {
      int jt = 2 * w + j;
      bfrag8 b = *(const bfrag8*)(Wot + (size_t)(jt * 16 + c) * 512 + kc * 32 + quad * 8);
      acc[j][kc & 1] = __builtin_amdgcn_mfma_f32_16x16x32_bf16(a[kc], b, acc[j][kc & 1], 0, 0, 0);
    }
  }
  float xv[2][4];
  #pragma unroll
  for (int j = 0; j < 2; ++j) {
    int jt = 2 * w + j;
    float bv = bo[jt * 16 + c];
    #pragma unroll
    for (int r = 0; r < 4; ++r) {
      int il = quad * 4 + r;
      size_t idx = (size_t)(r0 + il) * 64 + jt * 16 + c;
      float v = X[idx] + (acc[j][0][r] + acc[j][1][r]) + bv;
      X[idx] = v;
      xv[j][r] = v;
    }
  }
  // per-row partial sums over this wave's 32 cols
  #pragma unroll
  for (int r = 0; r < 4; ++r) {
    float s = xv[0][r] + xv[1][r];
    float q = xv[0][r] * xv[0][r] + xv[1][r] * xv[1][r];
    #pragma unroll
    for (int o = 8; o; o >>= 1) { s += __shfl_xor(s, o); q += __shfl_xor(q, o); }
    if (c == 0) { lnp[w][quad * 4 + r][0] = s; lnp[w][quad * 4 + r][1] = q; }
  }
  __syncthreads();
  // LN2 -> xa2 (this wave's cols)
  #pragma unroll
  for (int r = 0; r < 4; ++r) {
    int il = quad * 4 + r;
    float s = lnp[0][il][0] + lnp[1][il][0];
    float q = lnp[0][il][1] + lnp[1][il][1];
    float m = s * (1.f / 64.f);
    float rs = rsqrtf(q * (1.f / 64.f) - m * m + 1e-5f);
    #pragma unroll
    for (int j = 0; j < 2; ++j) {
      int n = (2 * w + j) * 16 + c;
      xa2[il * 72 + n] = f2b((xv[j][r] - m) * rs * g2[n] + bb2[n]);
    }
  }
  __syncthreads();
  // ---- FF1: wave w computes h-cols jt in {8w .. 8w+7} ----
  const uint16_t* xrow = xa2 + c * 72;
  bfrag8 a0 = *(const bfrag8*)(xrow + quad * 8);
  bfrag8 a1 = *(const bfrag8*)(xrow + 32 + quad * 8);
  #pragma unroll
  for (int jj = 0; jj < 8; ++jj) {
    int jt = 8 * w + jj;
    bfrag8 b0  = *(const bfrag8*)(W1t + (size_t)(jt * 16 + c) * 64 + quad * 8);
    bfrag8 b1f = *(const bfrag8*)(W1t + (size_t)(jt * 16 + c) * 64 + 32 + quad * 8);
    ffrag4 z = {0.f, 0.f, 0.f, 0.f};
    z = __builtin_amdgcn_mfma_f32_16x16x32_bf16(a0, b0, z, 0, 0, 0);
    z = __builtin_amdgcn_mfma_f32_16x16x32_bf16(a1, b1f, z, 0, 0, 0);
    float bv = b1[jt * 16 + c];
    #pragma unroll
    for (int r = 0; r < 4; ++r) {
      float zz = z[r] + bv;
      float hg = 0.5f * zz * (1.f + erff(zz * 0.7071067811865476f));
      ha[(quad * 4 + r) * 264 + jt * 16 + c] = f2b(hg);
    }
  }
  __syncthreads();
  // ---- FF2: wave w computes out cols jt in {2w, 2w+1} ----
  ffrag4 o2[2][2];
  #pragma unroll
  for (int j = 0; j < 2; ++j)
    #pragma unroll
    for (int p = 0; p < 2; ++p) o2[j][p] = (ffrag4){0.f, 0.f, 0.f, 0.f};
  #pragma unroll
  for (int kc = 0; kc < 8; ++kc) {
    bfrag8 pa = *(const bfrag8*)(ha + c * 264 + kc * 32 + quad * 8);
    #pragma unroll
    for (int j = 0; j < 2; ++j) {
      int jt = 2 * w + j;
      bfrag8 vb = *(const bfrag8*)(W2t + (size_t)(jt * 16 + c) * 256 + kc * 32 + quad * 8);
      o2[j][kc & 1] = __builtin_amdgcn_mfma_f32_16x16x32_bf16(pa, vb, o2[j][kc & 1], 0, 0, 0);
    }
  }
  float yv[2][4];
  #pragma unroll
  for (int j = 0; j < 2; ++j) {
    int jt = 2 * w + j;
    float bv = b2[jt * 16 + c];
    #pragma unroll
    for (int r = 0; r < 4; ++r) {
      int il = quad * 4 + r;
      size_t idx = (size_t)(r0 + il) * 64 + jt * 16 + c;
      float v = X[idx] + (o2[j][0][r] + o2[j][1][r]) + bv;
      X[idx] = v;
      yv[j][r] = v;
    }
  }
  #pragma unroll
  for (int r = 0; r < 4; ++r) {
    float s = yv[0][r] + yv[1][r];
    float q = yv[0][r] * yv[0][r] + yv[1][r] * yv[1][r];
    #pragma unroll
    for (int o = 8; o; o >>= 1) { s += __shfl_xor(s, o); q += __shfl_xor(q, o); }
    if (c == 0) { lnp[w][quad * 4 + r][0] = s; lnp[w][quad * 4 + r][1] = q; }
  }
  __syncthreads();
  #pragma unroll
  for (int r = 0; r < 4; ++r) {
    int il = quad * 4 + r;
    float s = lnp[0][il][0] + lnp[1][il][0];
    float q = lnp[0][il][1] + lnp[1][il][1];
    float m = s * (1.f / 64.f);
    float rs = rsqrtf(q * (1.f / 64.f) - m * m + 1e-5f);
    #pragma unroll
    for (int j = 0; j < 2; ++j) {
      int n = (2 * w + j) * 16 + c;
      XnOut[(size_t)(r0 + il) * 64 + n] = f2b((yv[j][r] - m) * rs * gn[n] + bbn[n]);
    }
  }
}

// ---- swap cls tokens between streams; refresh Xn (LN1 layer0) for those rows ----
__global__ void k_xchg(float* __restrict__ X, uint16_t* __restrict__ Xn,
                       const float* __restrict__ g, const float* __restrict__ bb) {
  int b = blockIdx.x, d = threadIdx.x;   // 64 blocks x 64 threads (1 wave)
  size_t i0 = (size_t)(b * NTOK) * ND + d;
  size_t i1 = (size_t)((64 + b) * NTOK) * ND + d;
  float a = X[i0], cc = X[i1];
  X[i0] = cc; X[i1] = a;
  float s0 = cc, q0 = cc * cc, s1 = a, q1 = a * a;
  #pragma unroll
  for (int o = 32; o; o >>= 1) {
    s0 += __shfl_xor(s0, o); q0 += __shfl_xor(q0, o);
    s1 += __shfl_xor(s1, o); q1 += __shfl_xor(q1, o);
  }
  float m0 = s0 * (1.f / 64.f), rs0 = rsqrtf(q0 * (1.f / 64.f) - m0 * m0 + 1e-5f);
  float m1 = s1 * (1.f / 64.f), rs1 = rsqrtf(q1 * (1.f / 64.f) - m1 * m1 + 1e-5f);
  Xn[i0] = f2b((cc - m0) * rs0 * g[d] + bb[d]);
  Xn[i1] = f2b((a - m1) * rs1 * g[d] + bb[d]);
}

// ---- final: out = h_cls + l_cls ----
__global__ void k_out(const float* __restrict__ X, float* __restrict__ out) {
  int i = blockIdx.x * 64 + threadIdx.x;
  int b = i >> 6, d = i & 63;
  out[i] = X[(size_t)b * NTOK * ND + d] + X[(size_t)(64 + b) * NTOK * ND + d];
}

extern "C" void kernel_launch(void* const* d_in, const int* in_sizes, int n_in,
                              void* d_out, int out_size, void* d_ws, size_t ws_size,
                              hipStream_t stream) {
  const float* hsi   = (const float*)d_in[0];
  const float* lidar = (const float*)d_in[1];
  const float* cls_h = (const float*)d_in[2];
  const float* cls_l = (const float*)d_in[3];
  const float* pos_h = (const float*)d_in[4];
  const float* pos_l = (const float*)d_in[5];
  const float* fmg_w = (const float*)d_in[6];
  const float* ln1_g = (const float*)d_in[7];
  const float* ln1_b = (const float*)d_in[8];
  const float* qkv_w = (const float*)d_in[9];
  const float* out_w = (const float*)d_in[10];
  const float* out_b = (const float*)d_in[11];
  const float* ln2_g = (const float*)d_in[12];
  const float* ln2_b = (const float*)d_in[13];
  const float* ff_w1 = (const float*)d_in[14];
  const float* ff_b1 = (const float*)d_in[15];
  const float* ff_w2 = (const float*)d_in[16];
  const float* ff_b2 = (const float*)d_in[17];

  char* ws = (char*)d_ws;
  float*    X    = (float*)ws;                       // 7,405,568 B
  float*    sdfm = (float*)(ws + 7405568);           // 16,384 B
  uint16_t* Xn   = (uint16_t*)(ws + 7421952);        // 3,702,784 B
  uint16_t* Og   = (uint16_t*)(ws + 11124736);       // 29,622,272 B
  uint16_t* Wqv  = (uint16_t*)(ws + 40747008);       // 524,288 B
  uint16_t* Wo   = (uint16_t*)(ws + 41271296);       // 262,144 B
  uint16_t* W1   = (uint16_t*)(ws + 41533440);       // 131,072 B
  uint16_t* W2   = (uint16_t*)(ws + 41664512);       // 131,072 B -> end 41,795,584

  k_wconv<<<2048, 256, 0, stream>>>(qkv_w, out_w, ff_w1, ff_w2, Wqv, Wo, W1, W2);
  k_dfm<<<NB, 128, 0, stream>>>(hsi, lidar, fmg_w, sdfm);
  k_build<<<NROWS, 64, 0, stream>>>(hsi, cls_h, cls_l, pos_h, pos_l,
                                    ln1_g, ln1_b, X, Xn);
  for (int pass = 0; pass < 2; ++pass) {
    for (int ly = 0; ly < NDEPTH; ++ly) {
      int nx = (ly + 1) & 3;   // next layer's LN1 params (harmless on final layer)
      k_fattn<<<NSB * NH, 512, 0, stream>>>(Xn, Wqv + (size_t)ly * 65536, sdfm, Og);
      k_pf<<<NROWS / 16, 128, 0, stream>>>(Og, Wo + (size_t)ly * 32768, out_b + ly * ND,
                                           X, ln2_g + ly * ND, ln2_b + ly * ND,
                                           W1 + (size_t)ly * 16384, ff_b1 + ly * NMLP,
                                           W2 + (size_t)ly * 16384, ff_b2 + ly * ND,
                                           ln1_g + nx * ND, ln1_b + nx * ND, Xn);
    }
    if (pass == 0) k_xchg<<<64, 64, 0, stream>>>(X, Xn, ln1_g, ln1_b);
  }
  k_out<<<64, 64, 0, stream>>>(X, (float*)d_out);
}